// Round 10
// baseline (319.915 us; speedup 1.0000x reference)
//
#include <hip/hip_runtime.h>

typedef unsigned short u16;
typedef unsigned int u32;
typedef unsigned long long u64;
typedef __attribute__((ext_vector_type(8))) __bf16 bf16x8;
typedef __attribute__((ext_vector_type(8))) _Float16 f16x8;
typedef __attribute__((ext_vector_type(4))) float f32x4;

#define DEVI __device__ __forceinline__

DEVI float bf2f(u16 u) { u32 x = ((u32)u) << 16; return __uint_as_float(x); }
DEVI u16 f2bf(float f) {
  u32 u = __float_as_uint(f);
  return (u16)((u + 0x7FFFu + ((u >> 16) & 1u)) >> 16);
}
DEVI u16 h_bits(_Float16 h) { return __builtin_bit_cast(u16, h); }
DEVI void gload_lds16(const void* g, void* l) {
  __builtin_amdgcn_global_load_lds((const __attribute__((address_space(1))) void*)g,
                                   (__attribute__((address_space(3))) void*)l, 16, 0, 0);
}
// bijective XCD-aware block swizzle
DEVI void swz_block(int& bx, int& by) {
  int gx = gridDim.x;
  int nwg = gx * gridDim.y;
  int wg = blockIdx.y * gx + blockIdx.x;
  int q = nwg >> 3, rr = nwg & 7, xcd = wg & 7, idx = wg >> 3;
  int s = (xcd < rr ? xcd * (q + 1) : rr * (q + 1) + (xcd - rr) * q) + idx;
  bx = s % gx;
  by = s / gx;
}

// ---------------- transpose f32 -> bf16 (out[C][R] = bf16(in[R][C])) ----------------
__global__ __launch_bounds__(256) void transpose_k(const float* __restrict__ in,
                                                   u16* __restrict__ out, int R, int C) {
  __shared__ float tile[32][33];
  int c0 = blockIdx.x * 32, r0 = blockIdx.y * 32;
  int tx = threadIdx.x, ty = threadIdx.y;  // (32,8)
#pragma unroll
  for (int k = 0; k < 4; k++)
    tile[ty + 8 * k][tx] = in[(size_t)(r0 + ty + 8 * k) * C + c0 + tx];
  __syncthreads();
#pragma unroll
  for (int k = 0; k < 4; k++) {
    float v = tile[tx][ty + 8 * k];
    out[(size_t)(c0 + ty + 8 * k) * R + r0 + tx] = f2bf(v);
  }
}

// ---------------- LayerNorm: 1024 cols, one block per row ----------------
__global__ __launch_bounds__(256) void ln_kernel(const float* __restrict__ x,
                                                 const float* __restrict__ g,
                                                 const float* __restrict__ b,
                                                 u16* __restrict__ obf,
                                                 u16* __restrict__ oh,
                                                 u16* __restrict__ ol) {
  int row = blockIdx.x;
  const float* xr = x + (size_t)row * 1024;
  float vals[4];
  float s = 0.f, s2 = 0.f;
#pragma unroll
  for (int i = 0; i < 4; i++) {
    float v = xr[threadIdx.x + i * 256];
    vals[i] = v; s += v; s2 += v * v;
  }
#pragma unroll
  for (int off = 32; off > 0; off >>= 1) {
    s += __shfl_down(s, off);
    s2 += __shfl_down(s2, off);
  }
  __shared__ float red[8];
  int wid = threadIdx.x >> 6;
  if ((threadIdx.x & 63) == 0) { red[wid] = s; red[4 + wid] = s2; }
  __syncthreads();
  if (threadIdx.x == 0) {
    float a = red[0] + red[1] + red[2] + red[3];
    float a2 = red[4] + red[5] + red[6] + red[7];
    float mu = a * (1.0f / 1024.0f);
    red[0] = mu;
    red[1] = a2 * (1.0f / 1024.0f) - mu * mu;
  }
  __syncthreads();
  float mu = red[0];
  float inv = 1.0f / sqrtf(red[1] + 1e-5f);
#pragma unroll
  for (int i = 0; i < 4; i++) {
    int c = threadIdx.x + i * 256;
    float y = (vals[i] - mu) * inv * g[c] + b[c];
    if (obf) obf[(size_t)row * 1024 + c] = f2bf(y);
    if (oh) {
      _Float16 hh = (_Float16)y;
      _Float16 ll = (_Float16)(y - (float)hh);
      oh[(size_t)row * 1024 + c] = h_bits(hh);
      ol[(size_t)row * 1024 + c] = h_bits(ll);
    }
  }
}

// ---- W2r_t[n][c] = sum_d Wqk[c][h*64+d]*rot[d][rj], f64 acc, f16 hi/lo split -------
__global__ __launch_bounds__(256) void w2r_kernel(const float* __restrict__ wqk,
                                                  const float* __restrict__ rot,
                                                  u16* __restrict__ w2rh,
                                                  u16* __restrict__ w2rl) {
  int idx = blockIdx.x * 256 + threadIdx.x;  // < 512*1024
  int n = idx >> 10, c = idx & 1023;
  int h = n >> 5, rj = n & 31;
  const float* wp = wqk + (size_t)c * 1024 + h * 64;
  double acc = 0.0;
  for (int d = 0; d < 64; d++) acc += (double)wp[d] * (double)rot[d * 32 + rj];
  _Float16 hh = (_Float16)acc;
  _Float16 ll = (_Float16)(acc - (double)hh);
  w2rh[idx] = h_bits(hh);
  w2rl[idx] = h_bits(ll);
}

// ---- rotated[4096,512] = A @ B^T via f16-split MFMA: Ah*Bh + Ah*Bl + Al*Bh ---------
__global__ __launch_bounds__(256) void gemm_rot_split(const u16* __restrict__ Ah,
                                                      const u16* __restrict__ Al,
                                                      const u16* __restrict__ Bh,
                                                      const u16* __restrict__ Bl,
                                                      float* __restrict__ C) {
  __shared__ __align__(16) u16 Ash[128 * 32];
  __shared__ __align__(16) u16 Asl[128 * 32];
  __shared__ __align__(16) u16 Bsh[64 * 32];
  __shared__ __align__(16) u16 Bsl[64 * 32];
  int tid = threadIdx.x;
  int bx, by;
  swz_block(bx, by);
  int m0 = by * 128, n0 = bx * 64;
  int w = tid >> 6, l = tid & 63, lr = l & 15, g = l >> 4;
  int wm = w >> 1, wn = w & 1;
  f32x4 acc[4][2];
#pragma unroll
  for (int i = 0; i < 4; i++)
#pragma unroll
    for (int j = 0; j < 2; j++) { f32x4 z = {0.f, 0.f, 0.f, 0.f}; acc[i][j] = z; }
  for (int k0 = 0; k0 < 1024; k0 += 32) {
    __syncthreads();
#pragma unroll
    for (int e = 0; e < 2; e++) {
      int idx = e * 256 + tid;
      const u16* ga = Ah + (size_t)(m0 + (idx >> 2)) * 1024 + k0 + (idx & 3) * 8;
      gload_lds16(ga, &Ash[(e * 256 + w * 64) * 8]);
      const u16* gl = Al + (size_t)(m0 + (idx >> 2)) * 1024 + k0 + (idx & 3) * 8;
      gload_lds16(gl, &Asl[(e * 256 + w * 64) * 8]);
    }
    {
      const u16* gb = Bh + (size_t)(n0 + (tid >> 2)) * 1024 + k0 + (tid & 3) * 8;
      gload_lds16(gb, &Bsh[(w * 64) * 8]);
      const u16* gb2 = Bl + (size_t)(n0 + (tid >> 2)) * 1024 + k0 + (tid & 3) * 8;
      gload_lds16(gb2, &Bsl[(w * 64) * 8]);
    }
    __syncthreads();
    f16x8 ah[4], al[4], bh[2], bl[2];
#pragma unroll
    for (int mt = 0; mt < 4; mt++) {
      ah[mt] = *(const f16x8*)&Ash[(wm * 64 + mt * 16 + lr) * 32 + g * 8];
      al[mt] = *(const f16x8*)&Asl[(wm * 64 + mt * 16 + lr) * 32 + g * 8];
    }
#pragma unroll
    for (int nt = 0; nt < 2; nt++) {
      bh[nt] = *(const f16x8*)&Bsh[(wn * 32 + nt * 16 + lr) * 32 + g * 8];
      bl[nt] = *(const f16x8*)&Bsl[(wn * 32 + nt * 16 + lr) * 32 + g * 8];
    }
#pragma unroll
    for (int mt = 0; mt < 4; mt++)
#pragma unroll
      for (int nt = 0; nt < 2; nt++) {
        acc[mt][nt] = __builtin_amdgcn_mfma_f32_16x16x32_f16(ah[mt], bh[nt], acc[mt][nt], 0, 0, 0);
        acc[mt][nt] = __builtin_amdgcn_mfma_f32_16x16x32_f16(ah[mt], bl[nt], acc[mt][nt], 0, 0, 0);
        acc[mt][nt] = __builtin_amdgcn_mfma_f32_16x16x32_f16(al[mt], bh[nt], acc[mt][nt], 0, 0, 0);
      }
  }
#pragma unroll
  for (int mt = 0; mt < 4; mt++)
#pragma unroll
    for (int nt = 0; nt < 2; nt++)
#pragma unroll
      for (int r = 0; r < 4; r++) {
        int row = m0 + wm * 64 + mt * 16 + g * 4 + r;
        int col = n0 + wn * 32 + nt * 16 + lr;
        C[(size_t)row * 512 + col] = acc[mt][nt][r];
      }
}

// ---------------- buckets: argmax over [v, -v] of 16 projections ----------------
__global__ __launch_bounds__(256) void bucket_kernel(const float* __restrict__ rotated,
                                                     int* __restrict__ buckets) {
  int gid = blockIdx.x * 256 + threadIdx.x;  // < 131072
  int bh = gid >> 12;
  int rem = gid & 4095;
  int r = rem >> 11, t = rem & 2047;
  int b = bh >> 4, h = bh & 15;
  const float* rp = rotated + (size_t)(b * 2048 + t) * 512 + h * 32 + r * 16;
  float v16[16];
#pragma unroll
  for (int j = 0; j < 16; j++) v16[j] = rp[j];
  float bv = v16[0];
  int bi = 0;
#pragma unroll
  for (int jj = 1; jj < 32; jj++) {
    float v = (jj < 16) ? v16[jj] : -v16[jj - 16];
    if (v > bv) { bv = v; bi = jj; }
  }
  buckets[bh * 4096 + r * 2048 + t] = bi + r * 32;
}

// ------- stable counting sort per (b,h): wave-parallel multisplit (ballot) ---------
__global__ __launch_bounds__(256) void sort_kernel(const int* __restrict__ buckets,
                                                   int* __restrict__ st,
                                                   int* __restrict__ undo) {
  int bh = blockIdx.x;
  __shared__ unsigned char bk[4096];
  __shared__ unsigned char rnk[4096];
  __shared__ int cnt[64 * 64];  // [chunk][bucket]
  __shared__ int base[64];
  int tid = threadIdx.x;
  int w = tid >> 6, lane = tid & 63;
  for (int i = tid; i < 4096; i += 256) bk[i] = (unsigned char)buckets[bh * 4096 + i];
  for (int i = tid; i < 4096; i += 256) cnt[i] = 0;
  __syncthreads();
  u64 lmask = (lane == 63) ? 0x7FFFFFFFFFFFFFFFull : ((1ull << lane) - 1ull);
#pragma unroll
  for (int it = 0; it < 16; ++it) {
    int c = w * 16 + it;
    int i = c * 64 + lane;
    int b = bk[i];
    u64 m = ~0ull;
#pragma unroll
    for (int k = 0; k < 6; k++) {
      u64 bal = __ballot((b >> k) & 1);
      m &= ((b >> k) & 1) ? bal : ~bal;
    }
    int r = __popcll(m & lmask);
    rnk[i] = (unsigned char)r;
    if (r == 0) cnt[c * 64 + b] = __popcll(m);
  }
  __syncthreads();
  if (tid < 64) {
    int acc = 0;
    for (int c = 0; c < 64; c++) {
      int t = cnt[c * 64 + tid];
      cnt[c * 64 + tid] = acc;
      acc += t;
    }
    base[tid] = acc;
  }
  __syncthreads();
  if (tid == 0) {
    int acc = 0;
    for (int b = 0; b < 64; b++) { int t = base[b]; base[b] = acc; acc += t; }
  }
  __syncthreads();
#pragma unroll
  for (int it = 0; it < 16; ++it) {
    int c = w * 16 + it;
    int i = c * 64 + lane;
    int b = bk[i];
    int pos = base[b] + cnt[c * 64 + b] + rnk[i];
    st[bh * 4096 + pos] = i & 2047;
    undo[bh * 4096 + i] = pos;
  }
}

// ------- chunked LSH attention: qkv fused layout [B*T][2048] (qk | v) -------
__global__ __launch_bounds__(256) void attn_kernel(const u16* __restrict__ qkv,
                                                   const int* __restrict__ st,
                                                   u16* __restrict__ so,
                                                   float* __restrict__ slog) {
  const int c = blockIdx.x;   // 0..63
  const int bh = blockIdx.y;  // 0..31
  const int b = bh >> 4, h = bh & 15;
  __shared__ __align__(16) u16 Q[64 * 72];
  __shared__ __align__(16) u16 Kl[128 * 72];
  __shared__ __align__(16) u16 Vt[64 * 136];
  __shared__ __align__(16) u16 P[64 * 136];
  __shared__ int bts[128];
  int tid = threadIdx.x;
  {
    int j = tid >> 1, half = tid & 1;
    int cc = (j < 64) ? c : ((c + 63) & 63);
    int t = st[bh * 4096 + cc * 64 + (j & 63)];
    size_t base = ((size_t)(b * 2048 + t)) * 2048 + h * 64 + half * 32;
    __align__(16) u16 raw[32];
    *(uint4*)(&raw[0]) = *(const uint4*)(qkv + base);
    *(uint4*)(&raw[8]) = *(const uint4*)(qkv + base + 8);
    *(uint4*)(&raw[16]) = *(const uint4*)(qkv + base + 16);
    *(uint4*)(&raw[24]) = *(const uint4*)(qkv + base + 24);
    float fv[32];
    float ss = 0.f;
#pragma unroll
    for (int e = 0; e < 32; e++) { fv[e] = bf2f(raw[e]); ss += fv[e] * fv[e]; }
    ss += __shfl_xor(ss, 1);
    float scale = 1.0f / (sqrtf(ss) + 1e-9f);
#pragma unroll
    for (int e = 0; e < 32; e++) Kl[j * 72 + half * 32 + e] = f2bf(fv[e] * scale);
    if (j < 64) {
#pragma unroll
      for (int e = 0; e < 32; e++) Q[j * 72 + half * 32 + e] = raw[e];
    }
    if (half == 0) bts[j] = t;
    __align__(16) u16 vr[32];
    *(uint4*)(&vr[0]) = *(const uint4*)(qkv + base + 1024);
    *(uint4*)(&vr[8]) = *(const uint4*)(qkv + base + 1032);
    *(uint4*)(&vr[16]) = *(const uint4*)(qkv + base + 1040);
    *(uint4*)(&vr[24]) = *(const uint4*)(qkv + base + 1048);
#pragma unroll
    for (int e = 0; e < 32; e++) Vt[(half * 32 + e) * 136 + j] = vr[e];
  }
  __syncthreads();
  int w = tid >> 6, l = tid & 63;
  int lr = l & 15, g = l >> 4;
  bf16x8 aq0 = *(const bf16x8*)&Q[(w * 16 + lr) * 72 + g * 8];
  bf16x8 aq1 = *(const bf16x8*)&Q[(w * 16 + lr) * 72 + 32 + g * 8];
  float dd[8][4];
#pragma unroll
  for (int n = 0; n < 8; n++) {
    f32x4 acc = {0.f, 0.f, 0.f, 0.f};
    bf16x8 b0 = *(const bf16x8*)&Kl[(n * 16 + lr) * 72 + g * 8];
    acc = __builtin_amdgcn_mfma_f32_16x16x32_bf16(aq0, b0, acc, 0, 0, 0);
    bf16x8 b1 = *(const bf16x8*)&Kl[(n * 16 + lr) * 72 + 32 + g * 8];
    acc = __builtin_amdgcn_mfma_f32_16x16x32_bf16(aq1, b1, acc, 0, 0, 0);
#pragma unroll
    for (int r = 0; r < 4; r++) dd[n][r] = acc[r];
  }
  int btq[4];
#pragma unroll
  for (int r = 0; r < 4; r++) btq[r] = bts[w * 16 + g * 4 + r];
  float mrow[4] = {-3e38f, -3e38f, -3e38f, -3e38f};
#pragma unroll
  for (int n = 0; n < 8; n++) {
    int btk = bts[n * 16 + lr];
#pragma unroll
    for (int r = 0; r < 4; r++) {
      float v = dd[n][r] * 0.125f;
      if (btq[r] == btk) v = -1e5f;
      dd[n][r] = v;
      mrow[r] = fmaxf(mrow[r], v);
    }
  }
#pragma unroll
  for (int off = 1; off < 16; off <<= 1)
#pragma unroll
    for (int r = 0; r < 4; r++) mrow[r] = fmaxf(mrow[r], __shfl_xor(mrow[r], off));
  float se[4] = {0.f, 0.f, 0.f, 0.f};
#pragma unroll
  for (int n = 0; n < 8; n++)
#pragma unroll
    for (int r = 0; r < 4; r++) se[r] += expf(dd[n][r] - mrow[r]);
#pragma unroll
  for (int off = 1; off < 16; off <<= 1)
#pragma unroll
    for (int r = 0; r < 4; r++) se[r] += __shfl_xor(se[r], off);
  float lse[4];
#pragma unroll
  for (int r = 0; r < 4; r++) lse[r] = mrow[r] + logf(se[r]);
#pragma unroll
  for (int n = 0; n < 8; n++)
#pragma unroll
    for (int r = 0; r < 4; r++) {
      float p = expf(dd[n][r] - lse[r]);
      P[(w * 16 + g * 4 + r) * 136 + n * 16 + lr] = f2bf(p);
    }
  if (lr == 0) {
#pragma unroll
    for (int r = 0; r < 4; r++)
      slog[bh * 4096 + c * 64 + w * 16 + g * 4 + r] = lse[r];
  }
  __syncthreads();
  f32x4 o[4];
#pragma unroll
  for (int n2 = 0; n2 < 4; n2++) { f32x4 z = {0.f, 0.f, 0.f, 0.f}; o[n2] = z; }
#pragma unroll
  for (int ks = 0; ks < 4; ks++) {
    bf16x8 ap = *(const bf16x8*)&P[(w * 16 + lr) * 136 + ks * 32 + g * 8];
#pragma unroll
    for (int n2 = 0; n2 < 4; n2++) {
      bf16x8 bv = *(const bf16x8*)&Vt[(n2 * 16 + lr) * 136 + ks * 32 + g * 8];
      o[n2] = __builtin_amdgcn_mfma_f32_16x16x32_bf16(ap, bv, o[n2], 0, 0, 0);
    }
  }
#pragma unroll
  for (int n2 = 0; n2 < 4; n2++)
#pragma unroll
    for (int r = 0; r < 4; r++)
      so[((size_t)bh * 4096 + c * 64 + w * 16 + g * 4 + r) * 64 + n2 * 16 + lr] =
          f2bf(o[n2][r]);
}

// ---------------- combine hash rounds + unsort ----------------
__global__ __launch_bounds__(256) void combine_kernel(const u16* __restrict__ so,
                                                      const float* __restrict__ slog,
                                                      const int* __restrict__ undo,
                                                      u16* __restrict__ attn_comb) {
  int bh = blockIdx.y;
  int b = bh >> 4, h = bh & 15;
  int t = blockIdx.x * 4 + (threadIdx.x >> 6);
  int d = threadIdx.x & 63;
  int j0 = undo[bh * 4096 + t];
  int j1 = undo[bh * 4096 + 2048 + t];
  float l0 = slog[bh * 4096 + j0], l1 = slog[bh * 4096 + j1];
  float m = fmaxf(l0, l1);
  float e0 = expf(l0 - m), e1 = expf(l1 - m);
  float inv = 1.0f / (e0 + e1);
  float o = (e0 * inv) * bf2f(so[((size_t)bh * 4096 + j0) * 64 + d]) +
            (e1 * inv) * bf2f(so[((size_t)bh * 4096 + j1) * 64 + d]);
  attn_comb[((size_t)(b * 2048 + t)) * 1024 + h * 64 + d] = f2bf(o);
}

// ---- bf16 MFMA GEMM, 128x128 tile, BK=32, 3-buf depth-2 -----------
template <int EPI>
__global__ __launch_bounds__(256) void gemm_bf16(const u16* __restrict__ A,
                                                 const u16* __restrict__ Bt,
                                                 void* __restrict__ Cv,
                                                 const float* __restrict__ bias,
                                                 const float* __restrict__ resid,
                                                 int M, int N, int K) {
  __shared__ __align__(16) u16 As[3][128 * 32];
  __shared__ __align__(16) u16 Bs[3][128 * 32];
  int tid = threadIdx.x;
  int bx, by;
  swz_block(bx, by);
  int m0 = by * 128, n0 = bx * 128;
  int w = tid >> 6, l = tid & 63, lr = l & 15, g = l >> 4;
  int wm = w >> 1, wn = w & 1;
  int sw = lr & 3;
  f32x4 acc[4][4];
#pragma unroll
  for (int i = 0; i < 4; i++)
#pragma unroll
    for (int j = 0; j < 4; j++) { f32x4 z = {0.f, 0.f, 0.f, 0.f}; acc[i][j] = z; }

  auto stage = [&](int buf, int k0) {
#pragma unroll
    for (int e = 0; e < 2; e++) {
      int idx = e * 256 + tid;
      int row = idx >> 2;
      int slot = (idx & 3) ^ (row & 3);
      gload_lds16(A + (size_t)(m0 + row) * K + k0 + slot * 8,
                  &As[buf][(e * 256 + w * 64) * 8]);
      gload_lds16(Bt + (size_t)(n0 + row) * K + k0 + slot * 8,
                  &Bs[buf][(e * 256 + w * 64) * 8]);
    }
  };

  const int NT = K >> 5;
  stage(0, 0);
  stage(1, 32);
  for (int t = 0; t < NT; ++t) {
    int cur = t % 3;
    if (t + 2 < NT) {
      stage((t + 2) % 3, (t + 2) << 5);
      asm volatile("s_waitcnt vmcnt(8)" ::: "memory");
    } else if (t + 1 < NT) {
      asm volatile("s_waitcnt vmcnt(4)" ::: "memory");
    } else {
      asm volatile("s_waitcnt vmcnt(0)" ::: "memory");
    }
    __builtin_amdgcn_s_barrier();
    bf16x8 af[4], bfr[4];
#pragma unroll
    for (int mt = 0; mt < 4; mt++)
      af[mt] = *(const bf16x8*)&As[cur][(wm * 64 + mt * 16 + lr) * 32 + (g ^ sw) * 8];
#pragma unroll
    for (int nt = 0; nt < 4; nt++)
      bfr[nt] = *(const bf16x8*)&Bs[cur][(wn * 64 + nt * 16 + lr) * 32 + (g ^ sw) * 8];
#pragma unroll
    for (int mt = 0; mt < 4; mt++)
#pragma unroll
      for (int nt = 0; nt < 4; nt++)
        acc[mt][nt] =
            __builtin_amdgcn_mfma_f32_16x16x32_bf16(af[mt], bfr[nt], acc[mt][nt], 0, 0, 0);
    __builtin_amdgcn_s_barrier();
  }
#pragma unroll
  for (int mt = 0; mt < 4; mt++)
#pragma unroll
    for (int nt = 0; nt < 4; nt++)
#pragma unroll
      for (int r = 0; r < 4; r++) {
        int row = m0 + wm * 64 + mt * 16 + g * 4 + r;
        int col = n0 + wn * 64 + nt * 16 + lr;
        float v = acc[mt][nt][r];
        if constexpr (EPI == 1) {
          v += resid[(size_t)row * N + col];
          ((float*)Cv)[(size_t)row * N + col] = v;
        } else if constexpr (EPI == 2) {
          v += bias[col];
          v = fmaxf(v, 0.f);
          ((u16*)Cv)[(size_t)row * N + col] = f2bf(v);
        } else if constexpr (EPI == 3) {
          v += bias[col] + resid[(size_t)row * N + col];
          ((float*)Cv)[(size_t)row * N + col] = v;
        } else {
          ((u16*)Cv)[(size_t)row * N + col] = f2bf(v);
        }
      }
}

// ---- bf16 MFMA GEMM, 128x64 tile, BK=64, 3-buf depth-2 ------------
template <int EPI>
__global__ __launch_bounds__(256) void gemm_bf16_n64(const u16* __restrict__ A,
                                                     const u16* __restrict__ Bt,
                                                     void* __restrict__ Cv,
                                                     const float* __restrict__ bias,
                                                     const float* __restrict__ resid,
                                                     int M, int N, int K) {
  __shared__ __align__(16) u16 As[3][128 * 64];
  __shared__ __align__(16) u16 Bs[3][64 * 64];
  int tid = threadIdx.x;
  int bx, by;
  swz_block(bx, by);
  int m0 = by * 128, n0 = bx * 64;
  int w = tid >> 6, l = tid & 63, lr = l & 15, g = l >> 4;
  int swa = lr & 7;
  f32x4 acc[2][4];
#pragma unroll
  for (int i = 0; i < 2; i++)
#pragma unroll
    for (int j = 0; j < 4; j++) { f32x4 z = {0.f, 0.f, 0.f, 0.f}; acc[i][j] = z; }

  auto stage = [&](int buf, int k0) {
#pragma unroll
    for (int e = 0; e < 4; e++) {
      int idx = e * 256 + tid;
      int row = idx >> 3, s = idx & 7;
      gload_lds16(A + (size_t)(m0 + row) * K + k0 + ((s ^ (row & 7)) * 8),
                  &As[buf][(e * 256 + w * 64) * 8]);
    }
#pragma unroll
    for (int e = 0; e < 2; e++) {
      int idx = e * 256 + tid;
      int row = idx >> 3, s = idx & 7;
      gload_lds16(Bt + (size_t)(n0 + row) * K + k0 + ((s ^ (row & 7)) * 8),
                  &Bs[buf][(e * 256 + w * 64) * 8]);
    }
  };

  const int NT = K >> 6;
  stage(0, 0);
  stage(1, 64);
  for (int t = 0; t < NT; ++t) {
    int cur = t % 3;
    if (t + 2 < NT) {
      stage((t + 2) % 3, (t + 2) << 6);
      asm volatile("s_waitcnt vmcnt(12)" ::: "memory");
    } else if (t + 1 < NT) {
      asm volatile("s_waitcnt vmcnt(6)" ::: "memory");
    } else {
      asm volatile("s_waitcnt vmcnt(0)" ::: "memory");
    }
    __builtin_amdgcn_s_barrier();
    bf16x8 af[2][2], bfr[4][2];
#pragma unroll
    for (int mt = 0; mt < 2; mt++)
#pragma unroll
      for (int ks = 0; ks < 2; ks++)
        af[mt][ks] = *(const bf16x8*)&As[cur][(w * 32 + mt * 16 + lr) * 64 +
                                             (((ks * 4 + g) ^ swa) * 8)];
#pragma unroll
    for (int nt = 0; nt < 4; nt++)
#pragma unroll
      for (int ks = 0; ks < 2; ks++)
        bfr[nt][ks] = *(const bf16x8*)&Bs[cur][(nt * 16 + lr) * 64 +
                                              (((ks * 4 + g) ^ swa) * 8)];
#pragma unroll
    for (int ks = 0; ks < 2; ks++)
#pragma unroll
      for (int mt = 0; mt < 2; mt++)
#pragma unroll
        for (int nt = 0; nt < 4; nt++)
          acc[mt][nt] = __builtin_amdgcn_mfma_f32_16x16x32_bf16(af[mt][ks], bfr[nt][ks],
                                                                acc[mt][nt], 0, 0, 0);
    __builtin_amdgcn_s_barrier();
  }
#pragma unroll
  for (int mt = 0; mt < 2; mt++)
#pragma unroll
    for (int nt = 0; nt < 4; nt++)
#pragma unroll
      for (int r = 0; r < 4; r++) {
        int row = m0 + w * 32 + mt * 16 + g * 4 + r;
        int col = n0 + nt * 16 + lr;
        float v = acc[mt][nt][r];
        if constexpr (EPI == 1) {
          v += resid[(size_t)row * N + col];
          ((float*)Cv)[(size_t)row * N + col] = v;
        } else if constexpr (EPI == 2) {
          v += bias[col];
          v = fmaxf(v, 0.f);
          ((u16*)Cv)[(size_t)row * N + col] = f2bf(v);
        } else if constexpr (EPI == 3) {
          v += bias[col] + resid[(size_t)row * N + col];
          ((float*)Cv)[(size_t)row * N + col] = v;
        } else {
          ((u16*)Cv)[(size_t)row * N + col] = f2bf(v);
        }
      }
}

// ---- bf16 MFMA GEMM, 256x256, BK=64, 8 waves, read-ahead 4-phase pipeline ---------
// Register-pipelined: each phase's ds_reads fill NEXT phase's fragments.
// Stage lead = 2 phases; uniform vmcnt(4); one barrier/phase; T2 swizzle; T5 setprio.
// NOTE: 128KB LDS means 1 block/CU ALWAYS; min-waves must be 1 or the 128-VGPR cap
// forces fragment spills (round-9 regression: WRITE_SIZE 32->125MB).
#define VMW4 asm volatile("s_waitcnt vmcnt(4)" ::: "memory")
#define VMW2 asm volatile("s_waitcnt vmcnt(2)" ::: "memory")
#define VMW0 asm volatile("s_waitcnt vmcnt(0)" ::: "memory")
#define BARR __builtin_amdgcn_s_barrier()
#define READ_A(dstv, bufv, qmv)                                                     \
  {                                                                                 \
    _Pragma("unroll") for (int mf = 0; mf < 4; mf++) {                              \
      _Pragma("unroll") for (int ks = 0; ks < 2; ks++) {                            \
        int row_ = wm * 128 + (qmv)*64 + mf * 16 + lr;                              \
        dstv[mf][ks] = *(const bf16x8*)&Al[bufv][row_ * 64 +                        \
                                                 (((ks * 4 + g) ^ (lr & 7)) * 8)];  \
      }                                                                             \
    }                                                                               \
  }
#define READ_B(dstv, bufv, qnv)                                                     \
  {                                                                                 \
    _Pragma("unroll") for (int nf = 0; nf < 2; nf++) {                              \
      _Pragma("unroll") for (int ks = 0; ks < 2; ks++) {                            \
        int row_ = wn * 64 + (qnv)*32 + nf * 16 + lr;                               \
        dstv[nf][ks] = *(const bf16x8*)&Bl[bufv][row_ * 64 +                        \
                                                 (((ks * 4 + g) ^ (lr & 7)) * 8)];  \
      }                                                                             \
    }                                                                               \
  }
#define MFMAQ(QM, QN, Av, Bv)                                                       \
  {                                                                                 \
    __builtin_amdgcn_s_setprio(1);                                                  \
    _Pragma("unroll") for (int ks = 0; ks < 2; ks++) {                              \
      _Pragma("unroll") for (int mf = 0; mf < 4; mf++) {                            \
        _Pragma("unroll") for (int nf = 0; nf < 2; nf++) {                          \
          acc[(QM)*4 + mf][(QN)*2 + nf] = __builtin_amdgcn_mfma_f32_16x16x32_bf16(  \
              Av[mf][ks], Bv[nf][ks], acc[(QM)*4 + mf][(QN)*2 + nf], 0, 0, 0);      \
        }                                                                           \
      }                                                                             \
    }                                                                               \
    __builtin_amdgcn_s_setprio(0);                                                  \
  }

template <int EPI>
__global__ __launch_bounds__(512, 1) void gemm_bf16_256(const u16* __restrict__ A,
                                                        const u16* __restrict__ Bt,
                                                        void* __restrict__ Cv,
                                                        const float* __restrict__ bias,
                                                        const float* __restrict__ resid,
                                                        int M, int N, int K) {
  __shared__ __align__(16) u16 Al[2][256 * 64];
  __shared__ __align__(16) u16 Bl[2][256 * 64];
  int tid = threadIdx.x;
  int bx, by;
  swz_block(bx, by);
  int m0 = by * 256, n0 = bx * 256;
  int w = tid >> 6, l = tid & 63, lr = l & 15, g = l >> 4;
  int wm = w >> 2, wn = w & 3;
  f32x4 acc[8][4];
#pragma unroll
  for (int i = 0; i < 8; i++)
#pragma unroll
    for (int j = 0; j < 4; j++) { f32x4 z = {0.f, 0.f, 0.f, 0.f}; acc[i][j] = z; }

  // staging unit u: 0=A qm0 (rows 0-63,128-191), 2=A qm1 (64-127,192-255)
  //                 1=B qn0 (32-row stripes at 0,64,128,192), 3=B qn1 (+32)
  auto stage_unit = [&](int u, int buf, int k0) {
#pragma unroll
    for (int j = 0; j < 2; j++) {
      int r = j * 64 + (tid >> 3);
      int s = tid & 7;
      int co = (s ^ (r & 7)) * 8;
      int r0 = j * 64 + (w << 3);
      const u16* src;
      u16* dst;
      if (u == 0) {
        int row = (r < 64) ? r : r + 64;
        int row0 = (r0 < 64) ? r0 : r0 + 64;
        src = A + (size_t)(m0 + row) * K + k0 + co;
        dst = &Al[buf][row0 * 64];
      } else if (u == 2) {
        int row = (r < 64) ? r + 64 : r + 128;
        int row0 = (r0 < 64) ? r0 + 64 : r0 + 128;
        src = A + (size_t)(m0 + row) * K + k0 + co;
        dst = &Al[buf][row0 * 64];
      } else if (u == 1) {
        int row = ((r >> 5) << 6) + (r & 31);
        int row0 = ((r0 >> 5) << 6) + (r0 & 31);
        src = Bt + (size_t)(n0 + row) * K + k0 + co;
        dst = &Bl[buf][row0 * 64];
      } else {
        int row = ((r >> 5) << 6) + 32 + (r & 31);
        int row0 = ((r0 >> 5) << 6) + 32 + (r0 & 31);
        src = Bt + (size_t)(n0 + row) * K + k0 + co;
        dst = &Bl[buf][row0 * 64];
      }
      gload_lds16(src, dst);
    }
  };

  bf16x8 aP[4][2], aQ[4][2], b0f[2][2], b1f[2][2];
  const int NT = K >> 6;  // even (K=1024 -> 16)
  // prologue: stage tile 0 into buf0, order B0,A0,A1,B1 (FIFO drain matches reads)
  stage_unit(1, 0, 0);
  stage_unit(0, 0, 0);
  stage_unit(2, 0, 0);
  stage_unit(3, 0, 0);
  VMW4;  // drains B0,A0 of tile 0
  BARR;
  READ_A(aP, 0, 0);   // A0@0
  READ_B(b0f, 0, 0);  // B0@0
  for (int it = 0; it < NT / 2; ++it) {
    int kE = (2 * it + 1) << 6;  // stage K for odd tile (always exists)
    int kO = (2 * it + 2) << 6;  // stage K for next even tile
    bool lastp = (it == NT / 2 - 1);
    // ---- EVEN tile (buf0); stage tile te+1 into buf1 ----
    stage_unit(1, 1, kE); VMW4; BARR; READ_A(aQ, 0, 1);  MFMAQ(0, 0, aP, b0f);
    stage_unit(0, 1, kE); VMW4; BARR; READ_B(b1f, 0, 1); MFMAQ(1, 0, aQ, b0f);
    stage_unit(2, 1, kE); VMW4; BARR; READ_B(b0f, 1, 0); MFMAQ(1, 1, aQ, b1f);
    stage_unit(3, 1, kE); VMW4; BARR; READ_A(aQ, 1, 0);  MFMAQ(0, 1, aP, b1f);
    // ---- ODD tile te+1 (buf1); stage tile te+2 into buf0 ----
    if (!lastp) { stage_unit(1, 0, kO); VMW4; } else { VMW2; }
    BARR; READ_A(aP, 1, 1);  MFMAQ(0, 0, aQ, b0f);
    if (!lastp) { stage_unit(0, 0, kO); VMW4; } else { VMW0; }
    BARR; READ_B(b1f, 1, 1); MFMAQ(1, 0, aP, b0f);
    if (!lastp) {
      stage_unit(2, 0, kO); VMW4; BARR; READ_B(b0f, 0, 0); MFMAQ(1, 1, aP, b1f);
      stage_unit(3, 0, kO); VMW4; BARR; READ_A(aP, 0, 0);  MFMAQ(0, 1, aQ, b1f);
    } else {
      BARR; MFMAQ(1, 1, aP, b1f);
      BARR; MFMAQ(0, 1, aQ, b1f);
    }
  }
#pragma unroll
  for (int mf = 0; mf < 8; mf++)
#pragma unroll
    for (int nf = 0; nf < 4; nf++)
#pragma unroll
      for (int r = 0; r < 4; r++) {
        int row = m0 + wm * 128 + mf * 16 + g * 4 + r;
        int col = n0 + wn * 64 + nf * 16 + lr;
        float v = acc[mf][nf][r];
        if constexpr (EPI == 1) {
          v += resid[(size_t)row * N + col];
          ((float*)Cv)[(size_t)row * N + col] = v;
        } else if constexpr (EPI == 2) {
          v += bias[col];
          v = fmaxf(v, 0.f);
          ((u16*)Cv)[(size_t)row * N + col] = f2bf(v);
        } else if constexpr (EPI == 3) {
          v += bias[col] + resid[(size_t)row * N + col];
          ((float*)Cv)[(size_t)row * N + col] = v;
        } else {
          ((u16*)Cv)[(size_t)row * N + col] = f2bf(v);
        }
      }
}

// ==================================================================================
extern "C" void kernel_launch(void* const* d_in, const int* in_sizes, int n_in,
                              void* d_out, int out_size, void* d_ws, size_t ws_size,
                              hipStream_t stream) {
  (void)in_sizes; (void)n_in; (void)out_size; (void)ws_size;
  const float* x    = (const float*)d_in[0];
  const float* ln1g = (const float*)d_in[2];
  const float* ln1b = (const float*)d_in[3];
  const float* ln2g = (const float*)d_in[4];
  const float* ln2b = (const float*)d_in[5];
  const float* Wqk  = (const float*)d_in[6];
  const float* Wv   = (const float*)d_in[7];
  const float* Wo   = (const float*)d_in[8];
  const float* rot  = (const float*)d_in[9];
  const float* W1   = (const float*)d_in[10];
  const float* b1   = (const float*)d_in[11];
  const float* W2   = (const float*)d_in[12];
  const float* b2   = (const float*)d_in[13];

  char* ws = (char*)d_ws;
  size_t off = 0;
  auto alloc = [&](size_t n) { size_t r = off; off += (n + 255) & ~(size_t)255; return r; };
  float* xn_f32  = (float*)(ws + alloc(4096ull * 1024 * 4));   // xn_h/xn_l, then x_attn
  u16*   xn_bf   = (u16*)(ws + alloc(4096ull * 1024 * 2));     // reused as h2
  u16*   wqkv_t  = (u16*)(ws + alloc(2048ull * 1024 * 2));     // [2048][1024] qk^T | v^T
  u16*   wo_t    = (u16*)(ws + alloc(1024ull * 1024 * 2));
  u16*   w1_t    = (u16*)(ws + alloc(4096ull * 1024 * 2));
  u16*   w2_t    = (u16*)(ws + alloc(4096ull * 1024 * 2));
  size_t qk_off  = alloc(4096ull * 2048 * 2);                  // qkv fused [4096][2048]
  u16*   qkvb    = (u16*)(ws + qk_off);
  float* w2r     = (float*)(ws + alloc(1024ull * 512 * 4));    // w2r_h/w2r_l f16
  float* rotated = (float*)(ws + alloc(4096ull * 512 * 4));    // reused as attn_comb
  int*   buckets = (int*)(ws + alloc(32ull * 4096 * 4));
  int*   stp     = (int*)(ws + alloc(32ull * 4096 * 4));
  int*   undo    = (int*)(ws + alloc(32ull * 4096 * 4));
  u16*   so      = (u16*)(ws + alloc(32ull * 4096 * 64 * 2));
  float* slog    = (float*)(ws + alloc(32ull * 4096 * 4));
  // aliases (lifetimes: donors dead before aliased writes)
  u16*   xn_h   = (u16*)xn_f32;          // LN1 out; dead after gemm_rot_split
  u16*   xn_l   = xn_h + 4096ull * 1024;
  float* x_attn = xn_f32;                // written after hash path done
  u16*   h2     = xn_bf;                 // written LN2; xn_bf dead after qkv gemm
  u16*   w2r_h  = (u16*)w2r;             // [512][1024] f16 hi
  u16*   w2r_l  = w2r_h + 512ull * 1024;
  u16*   attn_comb = (u16*)rotated;      // written combine; rotated dead after buckets
  u16*   f1 = (u16*)(ws + qk_off);       // 32MB spans qkvb..so; all dead before FFN1

  dim3 tb(32, 8);
  transpose_k<<<dim3(32, 32), tb, 0, stream>>>(Wqk, wqkv_t, 1024, 1024);
  transpose_k<<<dim3(32, 32), tb, 0, stream>>>(Wv, wqkv_t + 1024ull * 1024, 1024, 1024);
  transpose_k<<<dim3(32, 32), tb, 0, stream>>>(Wo, wo_t, 1024, 1024);
  transpose_k<<<dim3(128, 32), tb, 0, stream>>>(W1, w1_t, 1024, 4096);
  transpose_k<<<dim3(32, 128), tb, 0, stream>>>(W2, w2_t, 4096, 1024);

  ln_kernel<<<4096, 256, 0, stream>>>(x, ln1g, ln1b, xn_bf, xn_h, xn_l);

  // fused qk|v projection: [4096,1024] @ [2048,1024]^T -> [4096,2048]
  gemm_bf16<0><<<dim3(16, 32), 256, 0, stream>>>(xn_bf, wqkv_t, qkvb, nullptr, nullptr,
                                                 4096, 2048, 1024);

  w2r_kernel<<<2048, 256, 0, stream>>>(Wqk, rot, w2r_h, w2r_l);
  gemm_rot_split<<<dim3(8, 32), 256, 0, stream>>>(xn_h, xn_l, w2r_h, w2r_l, rotated);
  bucket_kernel<<<512, 256, 0, stream>>>(rotated, buckets);
  sort_kernel<<<32, 256, 0, stream>>>(buckets, stp, undo);
  attn_kernel<<<dim3(64, 32), 256, 0, stream>>>(qkvb, stp, so, slog);
  combine_kernel<<<dim3(512, 32), 256, 0, stream>>>(so, slog, undo, attn_comb);

  gemm_bf16_n64<1><<<dim3(16, 32), 256, 0, stream>>>(attn_comb, wo_t, x_attn, nullptr, x,
                                                     4096, 1024, 1024);
  ln_kernel<<<4096, 256, 0, stream>>>(x_attn, ln2g, ln2b, h2, nullptr, nullptr);
  // FFN1 on the 256^2 read-ahead pipelined kernel: grid 16x16 = 256 blocks = 1/CU
  gemm_bf16_256<2><<<dim3(16, 16), 512, 0, stream>>>(h2, w1_t, f1, b1, nullptr,
                                                     4096, 4096, 1024);
  gemm_bf16_n64<3><<<dim3(16, 32), 256, 0, stream>>>(f1, w2_t, (float*)d_out, b2, x_attn,
                                                     4096, 1024, 4096);
}

// Round 11
// 297.707 us; speedup vs baseline: 1.0746x; 1.0746x over previous
//
#include <hip/hip_runtime.h>

typedef unsigned short u16;
typedef unsigned int u32;
typedef unsigned long long u64;
typedef __attribute__((ext_vector_type(8))) __bf16 bf16x8;
typedef __attribute__((ext_vector_type(8))) _Float16 f16x8;
typedef __attribute__((ext_vector_type(4))) float f32x4;

#define DEVI __device__ __forceinline__

DEVI float bf2f(u16 u) { u32 x = ((u32)u) << 16; return __uint_as_float(x); }
DEVI u16 f2bf(float f) {
  u32 u = __float_as_uint(f);
  return (u16)((u + 0x7FFFu + ((u >> 16) & 1u)) >> 16);
}
DEVI u16 h_bits(_Float16 h) { return __builtin_bit_cast(u16, h); }
DEVI void gload_lds16(const void* g, void* l) {
  __builtin_amdgcn_global_load_lds((const __attribute__((address_space(1))) void*)g,
                                   (__attribute__((address_space(3))) void*)l, 16, 0, 0);
}
// bijective XCD-aware block swizzle
DEVI void swz_block(int& bx, int& by) {
  int gx = gridDim.x;
  int nwg = gx * gridDim.y;
  int wg = blockIdx.y * gx + blockIdx.x;
  int q = nwg >> 3, rr = nwg & 7, xcd = wg & 7, idx = wg >> 3;
  int s = (xcd < rr ? xcd * (q + 1) : rr * (q + 1) + (xcd - rr) * q) + idx;
  bx = s % gx;
  by = s / gx;
}

// ---------------- transpose f32 -> bf16 (out[C][R] = bf16(in[R][C])) ----------------
__global__ __launch_bounds__(256) void transpose_k(const float* __restrict__ in,
                                                   u16* __restrict__ out, int R, int C) {
  __shared__ float tile[32][33];
  int c0 = blockIdx.x * 32, r0 = blockIdx.y * 32;
  int tx = threadIdx.x, ty = threadIdx.y;  // (32,8)
#pragma unroll
  for (int k = 0; k < 4; k++)
    tile[ty + 8 * k][tx] = in[(size_t)(r0 + ty + 8 * k) * C + c0 + tx];
  __syncthreads();
#pragma unroll
  for (int k = 0; k < 4; k++) {
    float v = tile[tx][ty + 8 * k];
    out[(size_t)(c0 + ty + 8 * k) * R + r0 + tx] = f2bf(v);
  }
}

// ---------------- LayerNorm: 1024 cols, one block per row ----------------
__global__ __launch_bounds__(256) void ln_kernel(const float* __restrict__ x,
                                                 const float* __restrict__ g,
                                                 const float* __restrict__ b,
                                                 u16* __restrict__ obf,
                                                 u16* __restrict__ oh,
                                                 u16* __restrict__ ol) {
  int row = blockIdx.x;
  const float* xr = x + (size_t)row * 1024;
  float vals[4];
  float s = 0.f, s2 = 0.f;
#pragma unroll
  for (int i = 0; i < 4; i++) {
    float v = xr[threadIdx.x + i * 256];
    vals[i] = v; s += v; s2 += v * v;
  }
#pragma unroll
  for (int off = 32; off > 0; off >>= 1) {
    s += __shfl_down(s, off);
    s2 += __shfl_down(s2, off);
  }
  __shared__ float red[8];
  int wid = threadIdx.x >> 6;
  if ((threadIdx.x & 63) == 0) { red[wid] = s; red[4 + wid] = s2; }
  __syncthreads();
  if (threadIdx.x == 0) {
    float a = red[0] + red[1] + red[2] + red[3];
    float a2 = red[4] + red[5] + red[6] + red[7];
    float mu = a * (1.0f / 1024.0f);
    red[0] = mu;
    red[1] = a2 * (1.0f / 1024.0f) - mu * mu;
  }
  __syncthreads();
  float mu = red[0];
  float inv = 1.0f / sqrtf(red[1] + 1e-5f);
#pragma unroll
  for (int i = 0; i < 4; i++) {
    int c = threadIdx.x + i * 256;
    float y = (vals[i] - mu) * inv * g[c] + b[c];
    if (obf) obf[(size_t)row * 1024 + c] = f2bf(y);
    if (oh) {
      _Float16 hh = (_Float16)y;
      _Float16 ll = (_Float16)(y - (float)hh);
      oh[(size_t)row * 1024 + c] = h_bits(hh);
      ol[(size_t)row * 1024 + c] = h_bits(ll);
    }
  }
}

// ---- W2r_t[n][c] = sum_d Wqk[c][h*64+d]*rot[d][rj], f64 acc, f16 hi/lo split -------
__global__ __launch_bounds__(256) void w2r_kernel(const float* __restrict__ wqk,
                                                  const float* __restrict__ rot,
                                                  u16* __restrict__ w2rh,
                                                  u16* __restrict__ w2rl) {
  int idx = blockIdx.x * 256 + threadIdx.x;  // < 512*1024
  int n = idx >> 10, c = idx & 1023;
  int h = n >> 5, rj = n & 31;
  const float* wp = wqk + (size_t)c * 1024 + h * 64;
  double acc = 0.0;
  for (int d = 0; d < 64; d++) acc += (double)wp[d] * (double)rot[d * 32 + rj];
  _Float16 hh = (_Float16)acc;
  _Float16 ll = (_Float16)(acc - (double)hh);
  w2rh[idx] = h_bits(hh);
  w2rl[idx] = h_bits(ll);
}

// ---- rotated[4096,512] = A @ B^T via f16-split MFMA: Ah*Bh + Ah*Bl + Al*Bh ---------
__global__ __launch_bounds__(256) void gemm_rot_split(const u16* __restrict__ Ah,
                                                      const u16* __restrict__ Al,
                                                      const u16* __restrict__ Bh,
                                                      const u16* __restrict__ Bl,
                                                      float* __restrict__ C) {
  __shared__ __align__(16) u16 Ash[128 * 32];
  __shared__ __align__(16) u16 Asl[128 * 32];
  __shared__ __align__(16) u16 Bsh[64 * 32];
  __shared__ __align__(16) u16 Bsl[64 * 32];
  int tid = threadIdx.x;
  int bx, by;
  swz_block(bx, by);
  int m0 = by * 128, n0 = bx * 64;
  int w = tid >> 6, l = tid & 63, lr = l & 15, g = l >> 4;
  int wm = w >> 1, wn = w & 1;
  f32x4 acc[4][2];
#pragma unroll
  for (int i = 0; i < 4; i++)
#pragma unroll
    for (int j = 0; j < 2; j++) { f32x4 z = {0.f, 0.f, 0.f, 0.f}; acc[i][j] = z; }
  for (int k0 = 0; k0 < 1024; k0 += 32) {
    __syncthreads();
#pragma unroll
    for (int e = 0; e < 2; e++) {
      int idx = e * 256 + tid;
      const u16* ga = Ah + (size_t)(m0 + (idx >> 2)) * 1024 + k0 + (idx & 3) * 8;
      gload_lds16(ga, &Ash[(e * 256 + w * 64) * 8]);
      const u16* gl = Al + (size_t)(m0 + (idx >> 2)) * 1024 + k0 + (idx & 3) * 8;
      gload_lds16(gl, &Asl[(e * 256 + w * 64) * 8]);
    }
    {
      const u16* gb = Bh + (size_t)(n0 + (tid >> 2)) * 1024 + k0 + (tid & 3) * 8;
      gload_lds16(gb, &Bsh[(w * 64) * 8]);
      const u16* gb2 = Bl + (size_t)(n0 + (tid >> 2)) * 1024 + k0 + (tid & 3) * 8;
      gload_lds16(gb2, &Bsl[(w * 64) * 8]);
    }
    __syncthreads();
    f16x8 ah[4], al[4], bh[2], bl[2];
#pragma unroll
    for (int mt = 0; mt < 4; mt++) {
      ah[mt] = *(const f16x8*)&Ash[(wm * 64 + mt * 16 + lr) * 32 + g * 8];
      al[mt] = *(const f16x8*)&Asl[(wm * 64 + mt * 16 + lr) * 32 + g * 8];
    }
#pragma unroll
    for (int nt = 0; nt < 2; nt++) {
      bh[nt] = *(const f16x8*)&Bsh[(wn * 32 + nt * 16 + lr) * 32 + g * 8];
      bl[nt] = *(const f16x8*)&Bsl[(wn * 32 + nt * 16 + lr) * 32 + g * 8];
    }
#pragma unroll
    for (int mt = 0; mt < 4; mt++)
#pragma unroll
      for (int nt = 0; nt < 2; nt++) {
        acc[mt][nt] = __builtin_amdgcn_mfma_f32_16x16x32_f16(ah[mt], bh[nt], acc[mt][nt], 0, 0, 0);
        acc[mt][nt] = __builtin_amdgcn_mfma_f32_16x16x32_f16(ah[mt], bl[nt], acc[mt][nt], 0, 0, 0);
        acc[mt][nt] = __builtin_amdgcn_mfma_f32_16x16x32_f16(al[mt], bh[nt], acc[mt][nt], 0, 0, 0);
      }
  }
#pragma unroll
  for (int mt = 0; mt < 4; mt++)
#pragma unroll
    for (int nt = 0; nt < 2; nt++)
#pragma unroll
      for (int r = 0; r < 4; r++) {
        int row = m0 + wm * 64 + mt * 16 + g * 4 + r;
        int col = n0 + wn * 32 + nt * 16 + lr;
        C[(size_t)row * 512 + col] = acc[mt][nt][r];
      }
}

// ---------------- buckets: argmax over [v, -v] of 16 projections ----------------
__global__ __launch_bounds__(256) void bucket_kernel(const float* __restrict__ rotated,
                                                     int* __restrict__ buckets) {
  int gid = blockIdx.x * 256 + threadIdx.x;  // < 131072
  int bh = gid >> 12;
  int rem = gid & 4095;
  int r = rem >> 11, t = rem & 2047;
  int b = bh >> 4, h = bh & 15;
  const float* rp = rotated + (size_t)(b * 2048 + t) * 512 + h * 32 + r * 16;
  float v16[16];
#pragma unroll
  for (int j = 0; j < 16; j++) v16[j] = rp[j];
  float bv = v16[0];
  int bi = 0;
#pragma unroll
  for (int jj = 1; jj < 32; jj++) {
    float v = (jj < 16) ? v16[jj] : -v16[jj - 16];
    if (v > bv) { bv = v; bi = jj; }
  }
  buckets[bh * 4096 + r * 2048 + t] = bi + r * 32;
}

// ------- stable counting sort per (b,h): wave-parallel multisplit (ballot) ---------
__global__ __launch_bounds__(256) void sort_kernel(const int* __restrict__ buckets,
                                                   int* __restrict__ st,
                                                   int* __restrict__ undo) {
  int bh = blockIdx.x;
  __shared__ unsigned char bk[4096];
  __shared__ unsigned char rnk[4096];
  __shared__ int cnt[64 * 64];  // [chunk][bucket]
  __shared__ int base[64];
  int tid = threadIdx.x;
  int w = tid >> 6, lane = tid & 63;
  for (int i = tid; i < 4096; i += 256) bk[i] = (unsigned char)buckets[bh * 4096 + i];
  for (int i = tid; i < 4096; i += 256) cnt[i] = 0;
  __syncthreads();
  u64 lmask = (lane == 63) ? 0x7FFFFFFFFFFFFFFFull : ((1ull << lane) - 1ull);
#pragma unroll
  for (int it = 0; it < 16; ++it) {
    int c = w * 16 + it;
    int i = c * 64 + lane;
    int b = bk[i];
    u64 m = ~0ull;
#pragma unroll
    for (int k = 0; k < 6; k++) {
      u64 bal = __ballot((b >> k) & 1);
      m &= ((b >> k) & 1) ? bal : ~bal;
    }
    int r = __popcll(m & lmask);
    rnk[i] = (unsigned char)r;
    if (r == 0) cnt[c * 64 + b] = __popcll(m);
  }
  __syncthreads();
  if (tid < 64) {
    int acc = 0;
    for (int c = 0; c < 64; c++) {
      int t = cnt[c * 64 + tid];
      cnt[c * 64 + tid] = acc;
      acc += t;
    }
    base[tid] = acc;
  }
  __syncthreads();
  if (tid == 0) {
    int acc = 0;
    for (int b = 0; b < 64; b++) { int t = base[b]; base[b] = acc; acc += t; }
  }
  __syncthreads();
#pragma unroll
  for (int it = 0; it < 16; ++it) {
    int c = w * 16 + it;
    int i = c * 64 + lane;
    int b = bk[i];
    int pos = base[b] + cnt[c * 64 + b] + rnk[i];
    st[bh * 4096 + pos] = i & 2047;
    undo[bh * 4096 + i] = pos;
  }
}

// ------- chunked LSH attention: qkv fused layout [B*T][2048] (qk | v) -------
__global__ __launch_bounds__(256) void attn_kernel(const u16* __restrict__ qkv,
                                                   const int* __restrict__ st,
                                                   u16* __restrict__ so,
                                                   float* __restrict__ slog) {
  const int c = blockIdx.x;   // 0..63
  const int bh = blockIdx.y;  // 0..31
  const int b = bh >> 4, h = bh & 15;
  __shared__ __align__(16) u16 Q[64 * 72];
  __shared__ __align__(16) u16 Kl[128 * 72];
  __shared__ __align__(16) u16 Vt[64 * 136];
  __shared__ __align__(16) u16 P[64 * 136];
  __shared__ int bts[128];
  int tid = threadIdx.x;
  {
    int j = tid >> 1, half = tid & 1;
    int cc = (j < 64) ? c : ((c + 63) & 63);
    int t = st[bh * 4096 + cc * 64 + (j & 63)];
    size_t base = ((size_t)(b * 2048 + t)) * 2048 + h * 64 + half * 32;
    __align__(16) u16 raw[32];
    *(uint4*)(&raw[0]) = *(const uint4*)(qkv + base);
    *(uint4*)(&raw[8]) = *(const uint4*)(qkv + base + 8);
    *(uint4*)(&raw[16]) = *(const uint4*)(qkv + base + 16);
    *(uint4*)(&raw[24]) = *(const uint4*)(qkv + base + 24);
    float fv[32];
    float ss = 0.f;
#pragma unroll
    for (int e = 0; e < 32; e++) { fv[e] = bf2f(raw[e]); ss += fv[e] * fv[e]; }
    ss += __shfl_xor(ss, 1);
    float scale = 1.0f / (sqrtf(ss) + 1e-9f);
#pragma unroll
    for (int e = 0; e < 32; e++) Kl[j * 72 + half * 32 + e] = f2bf(fv[e] * scale);
    if (j < 64) {
#pragma unroll
      for (int e = 0; e < 32; e++) Q[j * 72 + half * 32 + e] = raw[e];
    }
    if (half == 0) bts[j] = t;
    __align__(16) u16 vr[32];
    *(uint4*)(&vr[0]) = *(const uint4*)(qkv + base + 1024);
    *(uint4*)(&vr[8]) = *(const uint4*)(qkv + base + 1032);
    *(uint4*)(&vr[16]) = *(const uint4*)(qkv + base + 1040);
    *(uint4*)(&vr[24]) = *(const uint4*)(qkv + base + 1048);
#pragma unroll
    for (int e = 0; e < 32; e++) Vt[(half * 32 + e) * 136 + j] = vr[e];
  }
  __syncthreads();
  int w = tid >> 6, l = tid & 63;
  int lr = l & 15, g = l >> 4;
  bf16x8 aq0 = *(const bf16x8*)&Q[(w * 16 + lr) * 72 + g * 8];
  bf16x8 aq1 = *(const bf16x8*)&Q[(w * 16 + lr) * 72 + 32 + g * 8];
  float dd[8][4];
#pragma unroll
  for (int n = 0; n < 8; n++) {
    f32x4 acc = {0.f, 0.f, 0.f, 0.f};
    bf16x8 b0 = *(const bf16x8*)&Kl[(n * 16 + lr) * 72 + g * 8];
    acc = __builtin_amdgcn_mfma_f32_16x16x32_bf16(aq0, b0, acc, 0, 0, 0);
    bf16x8 b1 = *(const bf16x8*)&Kl[(n * 16 + lr) * 72 + 32 + g * 8];
    acc = __builtin_amdgcn_mfma_f32_16x16x32_bf16(aq1, b1, acc, 0, 0, 0);
#pragma unroll
    for (int r = 0; r < 4; r++) dd[n][r] = acc[r];
  }
  int btq[4];
#pragma unroll
  for (int r = 0; r < 4; r++) btq[r] = bts[w * 16 + g * 4 + r];
  float mrow[4] = {-3e38f, -3e38f, -3e38f, -3e38f};
#pragma unroll
  for (int n = 0; n < 8; n++) {
    int btk = bts[n * 16 + lr];
#pragma unroll
    for (int r = 0; r < 4; r++) {
      float v = dd[n][r] * 0.125f;
      if (btq[r] == btk) v = -1e5f;
      dd[n][r] = v;
      mrow[r] = fmaxf(mrow[r], v);
    }
  }
#pragma unroll
  for (int off = 1; off < 16; off <<= 1)
#pragma unroll
    for (int r = 0; r < 4; r++) mrow[r] = fmaxf(mrow[r], __shfl_xor(mrow[r], off));
  float se[4] = {0.f, 0.f, 0.f, 0.f};
#pragma unroll
  for (int n = 0; n < 8; n++)
#pragma unroll
    for (int r = 0; r < 4; r++) se[r] += expf(dd[n][r] - mrow[r]);
#pragma unroll
  for (int off = 1; off < 16; off <<= 1)
#pragma unroll
    for (int r = 0; r < 4; r++) se[r] += __shfl_xor(se[r], off);
  float lse[4];
#pragma unroll
  for (int r = 0; r < 4; r++) lse[r] = mrow[r] + logf(se[r]);
#pragma unroll
  for (int n = 0; n < 8; n++)
#pragma unroll
    for (int r = 0; r < 4; r++) {
      float p = expf(dd[n][r] - lse[r]);
      P[(w * 16 + g * 4 + r) * 136 + n * 16 + lr] = f2bf(p);
    }
  if (lr == 0) {
#pragma unroll
    for (int r = 0; r < 4; r++)
      slog[bh * 4096 + c * 64 + w * 16 + g * 4 + r] = lse[r];
  }
  __syncthreads();
  f32x4 o[4];
#pragma unroll
  for (int n2 = 0; n2 < 4; n2++) { f32x4 z = {0.f, 0.f, 0.f, 0.f}; o[n2] = z; }
#pragma unroll
  for (int ks = 0; ks < 4; ks++) {
    bf16x8 ap = *(const bf16x8*)&P[(w * 16 + lr) * 136 + ks * 32 + g * 8];
#pragma unroll
    for (int n2 = 0; n2 < 4; n2++) {
      bf16x8 bv = *(const bf16x8*)&Vt[(n2 * 16 + lr) * 136 + ks * 32 + g * 8];
      o[n2] = __builtin_amdgcn_mfma_f32_16x16x32_bf16(ap, bv, o[n2], 0, 0, 0);
    }
  }
#pragma unroll
  for (int n2 = 0; n2 < 4; n2++)
#pragma unroll
    for (int r = 0; r < 4; r++)
      so[((size_t)bh * 4096 + c * 64 + w * 16 + g * 4 + r) * 64 + n2 * 16 + lr] =
          f2bf(o[n2][r]);
}

// ---------------- combine hash rounds + unsort ----------------
__global__ __launch_bounds__(256) void combine_kernel(const u16* __restrict__ so,
                                                      const float* __restrict__ slog,
                                                      const int* __restrict__ undo,
                                                      u16* __restrict__ attn_comb) {
  int bh = blockIdx.y;
  int b = bh >> 4, h = bh & 15;
  int t = blockIdx.x * 4 + (threadIdx.x >> 6);
  int d = threadIdx.x & 63;
  int j0 = undo[bh * 4096 + t];
  int j1 = undo[bh * 4096 + 2048 + t];
  float l0 = slog[bh * 4096 + j0], l1 = slog[bh * 4096 + j1];
  float m = fmaxf(l0, l1);
  float e0 = expf(l0 - m), e1 = expf(l1 - m);
  float inv = 1.0f / (e0 + e1);
  float o = (e0 * inv) * bf2f(so[((size_t)bh * 4096 + j0) * 64 + d]) +
            (e1 * inv) * bf2f(so[((size_t)bh * 4096 + j1) * 64 + d]);
  attn_comb[((size_t)(b * 2048 + t)) * 1024 + h * 64 + d] = f2bf(o);
}

// ---- bf16 MFMA GEMM, 128x128 tile, BK=32, 3-buf depth-2 -----------
template <int EPI>
__global__ __launch_bounds__(256) void gemm_bf16(const u16* __restrict__ A,
                                                 const u16* __restrict__ Bt,
                                                 void* __restrict__ Cv,
                                                 const float* __restrict__ bias,
                                                 const float* __restrict__ resid,
                                                 int M, int N, int K) {
  __shared__ __align__(16) u16 As[3][128 * 32];
  __shared__ __align__(16) u16 Bs[3][128 * 32];
  int tid = threadIdx.x;
  int bx, by;
  swz_block(bx, by);
  int m0 = by * 128, n0 = bx * 128;
  int w = tid >> 6, l = tid & 63, lr = l & 15, g = l >> 4;
  int wm = w >> 1, wn = w & 1;
  int sw = lr & 3;
  f32x4 acc[4][4];
#pragma unroll
  for (int i = 0; i < 4; i++)
#pragma unroll
    for (int j = 0; j < 4; j++) { f32x4 z = {0.f, 0.f, 0.f, 0.f}; acc[i][j] = z; }

  auto stage = [&](int buf, int k0) {
#pragma unroll
    for (int e = 0; e < 2; e++) {
      int idx = e * 256 + tid;
      int row = idx >> 2;
      int slot = (idx & 3) ^ (row & 3);
      gload_lds16(A + (size_t)(m0 + row) * K + k0 + slot * 8,
                  &As[buf][(e * 256 + w * 64) * 8]);
      gload_lds16(Bt + (size_t)(n0 + row) * K + k0 + slot * 8,
                  &Bs[buf][(e * 256 + w * 64) * 8]);
    }
  };

  const int NT = K >> 5;
  stage(0, 0);
  stage(1, 32);
  for (int t = 0; t < NT; ++t) {
    int cur = t % 3;
    if (t + 2 < NT) {
      stage((t + 2) % 3, (t + 2) << 5);
      asm volatile("s_waitcnt vmcnt(8)" ::: "memory");
    } else if (t + 1 < NT) {
      asm volatile("s_waitcnt vmcnt(4)" ::: "memory");
    } else {
      asm volatile("s_waitcnt vmcnt(0)" ::: "memory");
    }
    __builtin_amdgcn_s_barrier();
    bf16x8 af[4], bfr[4];
#pragma unroll
    for (int mt = 0; mt < 4; mt++)
      af[mt] = *(const bf16x8*)&As[cur][(wm * 64 + mt * 16 + lr) * 32 + (g ^ sw) * 8];
#pragma unroll
    for (int nt = 0; nt < 4; nt++)
      bfr[nt] = *(const bf16x8*)&Bs[cur][(wn * 64 + nt * 16 + lr) * 32 + (g ^ sw) * 8];
#pragma unroll
    for (int mt = 0; mt < 4; mt++)
#pragma unroll
      for (int nt = 0; nt < 4; nt++)
        acc[mt][nt] =
            __builtin_amdgcn_mfma_f32_16x16x32_bf16(af[mt], bfr[nt], acc[mt][nt], 0, 0, 0);
    __builtin_amdgcn_s_barrier();
  }
#pragma unroll
  for (int mt = 0; mt < 4; mt++)
#pragma unroll
    for (int nt = 0; nt < 4; nt++)
#pragma unroll
      for (int r = 0; r < 4; r++) {
        int row = m0 + wm * 64 + mt * 16 + g * 4 + r;
        int col = n0 + wn * 64 + nt * 16 + lr;
        float v = acc[mt][nt][r];
        if constexpr (EPI == 1) {
          v += resid[(size_t)row * N + col];
          ((float*)Cv)[(size_t)row * N + col] = v;
        } else if constexpr (EPI == 2) {
          v += bias[col];
          v = fmaxf(v, 0.f);
          ((u16*)Cv)[(size_t)row * N + col] = f2bf(v);
        } else if constexpr (EPI == 3) {
          v += bias[col] + resid[(size_t)row * N + col];
          ((float*)Cv)[(size_t)row * N + col] = v;
        } else {
          ((u16*)Cv)[(size_t)row * N + col] = f2bf(v);
        }
      }
}

// ---- bf16 MFMA GEMM, 128x64 tile, BK=64, 3-buf depth-2 ------------
template <int EPI>
__global__ __launch_bounds__(256) void gemm_bf16_n64(const u16* __restrict__ A,
                                                     const u16* __restrict__ Bt,
                                                     void* __restrict__ Cv,
                                                     const float* __restrict__ bias,
                                                     const float* __restrict__ resid,
                                                     int M, int N, int K) {
  __shared__ __align__(16) u16 As[3][128 * 64];
  __shared__ __align__(16) u16 Bs[3][64 * 64];
  int tid = threadIdx.x;
  int bx, by;
  swz_block(bx, by);
  int m0 = by * 128, n0 = bx * 64;
  int w = tid >> 6, l = tid & 63, lr = l & 15, g = l >> 4;
  int swa = lr & 7;
  f32x4 acc[2][4];
#pragma unroll
  for (int i = 0; i < 2; i++)
#pragma unroll
    for (int j = 0; j < 4; j++) { f32x4 z = {0.f, 0.f, 0.f, 0.f}; acc[i][j] = z; }

  auto stage = [&](int buf, int k0) {
#pragma unroll
    for (int e = 0; e < 4; e++) {
      int idx = e * 256 + tid;
      int row = idx >> 3, s = idx & 7;
      gload_lds16(A + (size_t)(m0 + row) * K + k0 + ((s ^ (row & 7)) * 8),
                  &As[buf][(e * 256 + w * 64) * 8]);
    }
#pragma unroll
    for (int e = 0; e < 2; e++) {
      int idx = e * 256 + tid;
      int row = idx >> 3, s = idx & 7;
      gload_lds16(Bt + (size_t)(n0 + row) * K + k0 + ((s ^ (row & 7)) * 8),
                  &Bs[buf][(e * 256 + w * 64) * 8]);
    }
  };

  const int NT = K >> 6;
  stage(0, 0);
  stage(1, 64);
  for (int t = 0; t < NT; ++t) {
    int cur = t % 3;
    if (t + 2 < NT) {
      stage((t + 2) % 3, (t + 2) << 6);
      asm volatile("s_waitcnt vmcnt(12)" ::: "memory");
    } else if (t + 1 < NT) {
      asm volatile("s_waitcnt vmcnt(6)" ::: "memory");
    } else {
      asm volatile("s_waitcnt vmcnt(0)" ::: "memory");
    }
    __builtin_amdgcn_s_barrier();
    bf16x8 af[2][2], bfr[4][2];
#pragma unroll
    for (int mt = 0; mt < 2; mt++)
#pragma unroll
      for (int ks = 0; ks < 2; ks++)
        af[mt][ks] = *(const bf16x8*)&As[cur][(w * 32 + mt * 16 + lr) * 64 +
                                             (((ks * 4 + g) ^ swa) * 8)];
#pragma unroll
    for (int nt = 0; nt < 4; nt++)
#pragma unroll
      for (int ks = 0; ks < 2; ks++)
        bfr[nt][ks] = *(const bf16x8*)&Bs[cur][(nt * 16 + lr) * 64 +
                                              (((ks * 4 + g) ^ swa) * 8)];
#pragma unroll
    for (int ks = 0; ks < 2; ks++)
#pragma unroll
      for (int mt = 0; mt < 2; mt++)
#pragma unroll
        for (int nt = 0; nt < 4; nt++)
          acc[mt][nt] = __builtin_amdgcn_mfma_f32_16x16x32_bf16(af[mt][ks], bfr[nt][ks],
                                                                acc[mt][nt], 0, 0, 0);
    __builtin_amdgcn_s_barrier();
  }
#pragma unroll
  for (int mt = 0; mt < 2; mt++)
#pragma unroll
    for (int nt = 0; nt < 4; nt++)
#pragma unroll
      for (int r = 0; r < 4; r++) {
        int row = m0 + w * 32 + mt * 16 + g * 4 + r;
        int col = n0 + nt * 16 + lr;
        float v = acc[mt][nt][r];
        if constexpr (EPI == 1) {
          v += resid[(size_t)row * N + col];
          ((float*)Cv)[(size_t)row * N + col] = v;
        } else if constexpr (EPI == 2) {
          v += bias[col];
          v = fmaxf(v, 0.f);
          ((u16*)Cv)[(size_t)row * N + col] = f2bf(v);
        } else if constexpr (EPI == 3) {
          v += bias[col] + resid[(size_t)row * N + col];
          ((float*)Cv)[(size_t)row * N + col] = v;
        } else {
          ((u16*)Cv)[(size_t)row * N + col] = f2bf(v);
        }
      }
}

// ---- bf16 MFMA GEMM, 256x256, BK=64, 8 waves, 4-phase/K-tile pipeline -------------
// Round-8 structure (single fragment set, no spill) + template-faithful read
// placement: each phase's ds_reads sit BEFORE its barrier, overlapping barrier-
// arrival skew and other waves' previous MFMAs. Cross-wave visibility: each
// phase's vmcnt drains the stripe that the NEXT phase reads, so every read's
// stripe is (vmcnt-by-all-waves + barrier)-confirmed one phase earlier.
// NOTE: dual-fragment read-ahead (r9/r10) spills regardless of launch_bounds
// (VGPR pinned at 128, WRITE_SIZE 32->125MB) — keep fragment footprint small.
#define BARR __builtin_amdgcn_s_barrier()
#define LOAD_A_Q(curv, qmv)                                                         \
  {                                                                                 \
    _Pragma("unroll") for (int mf = 0; mf < 4; mf++) {                              \
      _Pragma("unroll") for (int ks = 0; ks < 2; ks++) {                            \
        int row_ = wm * 128 + (qmv)*64 + mf * 16 + lr;                              \
        a[mf][ks] = *(const bf16x8*)&Al[curv][row_ * 64 +                           \
                                              (((ks * 4 + g) ^ (lr & 7)) * 8)];     \
      }                                                                             \
    }                                                                               \
  }
#define LOAD_B_Q(curv, qnv)                                                         \
  {                                                                                 \
    _Pragma("unroll") for (int nf = 0; nf < 2; nf++) {                              \
      _Pragma("unroll") for (int ks = 0; ks < 2; ks++) {                            \
        int row_ = wn * 64 + (qnv)*32 + nf * 16 + lr;                               \
        bfr[nf][ks] = *(const bf16x8*)&Bl[curv][row_ * 64 +                         \
                                                (((ks * 4 + g) ^ (lr & 7)) * 8)];   \
      }                                                                             \
    }                                                                               \
  }
#define MFMA_Q(QM, QN)                                                              \
  {                                                                                 \
    __builtin_amdgcn_s_setprio(1);                                                  \
    _Pragma("unroll") for (int ks = 0; ks < 2; ks++) {                              \
      _Pragma("unroll") for (int mf = 0; mf < 4; mf++) {                            \
        _Pragma("unroll") for (int nf = 0; nf < 2; nf++) {                          \
          acc[(QM)*4 + mf][(QN)*2 + nf] = __builtin_amdgcn_mfma_f32_16x16x32_bf16(  \
              a[mf][ks], bfr[nf][ks], acc[(QM)*4 + mf][(QN)*2 + nf], 0, 0, 0);      \
        }                                                                           \
      }                                                                             \
    }                                                                               \
    __builtin_amdgcn_s_setprio(0);                                                  \
  }

template <int EPI>
__global__ __launch_bounds__(512, 2) void gemm_bf16_256(const u16* __restrict__ A,
                                                        const u16* __restrict__ Bt,
                                                        void* __restrict__ Cv,
                                                        const float* __restrict__ bias,
                                                        const float* __restrict__ resid,
                                                        int M, int N, int K) {
  __shared__ __align__(16) u16 Al[2][256 * 64];
  __shared__ __align__(16) u16 Bl[2][256 * 64];
  int tid = threadIdx.x;
  int bx, by;
  swz_block(bx, by);
  int m0 = by * 256, n0 = bx * 256;
  int w = tid >> 6, l = tid & 63, lr = l & 15, g = l >> 4;
  int wm = w >> 2, wn = w & 3;
  f32x4 acc[8][4];
#pragma unroll
  for (int i = 0; i < 8; i++)
#pragma unroll
    for (int j = 0; j < 4; j++) { f32x4 z = {0.f, 0.f, 0.f, 0.f}; acc[i][j] = z; }

  // staging unit u: 0=A qm0 (rows 0-63,128-191), 2=A qm1 (64-127,192-255)
  //                 1=B qn0 (32-row stripes at 0,64,128,192), 3=B qn1 (+32)
  auto stage_unit = [&](int u, int buf, int k0) {
#pragma unroll
    for (int j = 0; j < 2; j++) {
      int r = j * 64 + (tid >> 3);
      int s = tid & 7;
      int co = (s ^ (r & 7)) * 8;
      int r0 = j * 64 + (w << 3);
      const u16* src;
      u16* dst;
      if (u == 0) {
        int row = (r < 64) ? r : r + 64;
        int row0 = (r0 < 64) ? r0 : r0 + 64;
        src = A + (size_t)(m0 + row) * K + k0 + co;
        dst = &Al[buf][row0 * 64];
      } else if (u == 2) {
        int row = (r < 64) ? r + 64 : r + 128;
        int row0 = (r0 < 64) ? r0 + 64 : r0 + 128;
        src = A + (size_t)(m0 + row) * K + k0 + co;
        dst = &Al[buf][row0 * 64];
      } else if (u == 1) {
        int row = ((r >> 5) << 6) + (r & 31);
        int row0 = ((r0 >> 5) << 6) + (r0 & 31);
        src = Bt + (size_t)(n0 + row) * K + k0 + co;
        dst = &Bl[buf][row0 * 64];
      } else {
        int row = ((r >> 5) << 6) + 32 + (r & 31);
        int row0 = ((r0 >> 5) << 6) + 32 + (r0 & 31);
        src = Bt + (size_t)(n0 + row) * K + k0 + co;
        dst = &Bl[buf][row0 * 64];
      }
      gload_lds16(src, dst);
    }
  };

  bf16x8 a[4][2], bfr[2][2];
  const int NT = K >> 6;
  // prologue: stage all 4 units of tile 0; confirm u0,u1 for ph0's early reads
  stage_unit(0, 0, 0);
  stage_unit(1, 0, 0);
  stage_unit(2, 0, 0);
  stage_unit(3, 0, 0);
  asm volatile("s_waitcnt vmcnt(4)" ::: "memory");  // drains u0(0),u1(0)
  BARR;                                             // all waves' stripes visible
  for (int t = 0; t < NT; ++t) {
    int cur = t & 1, nxt = cur ^ 1;
    int k1 = (t + 1) << 6;
    bool last = (t == NT - 1);
    // phase 0: (0,0); reads u0(t),u1(t) [confirmed by prev ph3 vmcnt+BARR];
    //          vmcnt drains u2(t) for ph1's early read
    if (!last) {
      stage_unit(0, nxt, k1);
      asm volatile("s_waitcnt vmcnt(4)" ::: "memory");
    } else {
      asm volatile("s_waitcnt vmcnt(2)" ::: "memory");
    }
    LOAD_A_Q(cur, 0);
    LOAD_B_Q(cur, 0);
    BARR;
    MFMA_Q(0, 0);
    BARR;
    // phase 1: (1,0); reads u2(t); vmcnt drains u3(t) for ph2
    if (!last) {
      stage_unit(1, nxt, k1);
      asm volatile("s_waitcnt vmcnt(4)" ::: "memory");
    } else {
      asm volatile("s_waitcnt vmcnt(0)" ::: "memory");
    }
    LOAD_A_Q(cur, 1);
    BARR;
    MFMA_Q(1, 0);
    BARR;
    // phase 2: (1,1); reads u3(t); nothing new to drain (ph3 rereads u0(t))
    if (!last) stage_unit(2, nxt, k1);
    LOAD_B_Q(cur, 1);
    BARR;
    MFMA_Q(1, 1);
    BARR;
    // phase 3: (0,1); re-reads u0(t) (long-confirmed);
    //          vmcnt drains u0(t+1),u1(t+1) for next tile's ph0
    if (!last) {
      stage_unit(3, nxt, k1);
      asm volatile("s_waitcnt vmcnt(4)" ::: "memory");
    }
    LOAD_A_Q(cur, 0);
    BARR;
    MFMA_Q(0, 1);
    BARR;
  }
#pragma unroll
  for (int mf = 0; mf < 8; mf++)
#pragma unroll
    for (int nf = 0; nf < 4; nf++)
#pragma unroll
      for (int r = 0; r < 4; r++) {
        int row = m0 + wm * 128 + mf * 16 + g * 4 + r;
        int col = n0 + wn * 64 + nf * 16 + lr;
        float v = acc[mf][nf][r];
        if constexpr (EPI == 1) {
          v += resid[(size_t)row * N + col];
          ((float*)Cv)[(size_t)row * N + col] = v;
        } else if constexpr (EPI == 2) {
          v += bias[col];
          v = fmaxf(v, 0.f);
          ((u16*)Cv)[(size_t)row * N + col] = f2bf(v);
        } else if constexpr (EPI == 3) {
          v += bias[col] + resid[(size_t)row * N + col];
          ((float*)Cv)[(size_t)row * N + col] = v;
        } else {
          ((u16*)Cv)[(size_t)row * N + col] = f2bf(v);
        }
      }
}

// ==================================================================================
extern "C" void kernel_launch(void* const* d_in, const int* in_sizes, int n_in,
                              void* d_out, int out_size, void* d_ws, size_t ws_size,
                              hipStream_t stream) {
  (void)in_sizes; (void)n_in; (void)out_size; (void)ws_size;
  const float* x    = (const float*)d_in[0];
  const float* ln1g = (const float*)d_in[2];
  const float* ln1b = (const float*)d_in[3];
  const float* ln2g = (const float*)d_in[4];
  const float* ln2b = (const float*)d_in[5];
  const float* Wqk  = (const float*)d_in[6];
  const float* Wv   = (const float*)d_in[7];
  const float* Wo   = (const float*)d_in[8];
  const float* rot  = (const float*)d_in[9];
  const float* W1   = (const float*)d_in[10];
  const float* b1   = (const float*)d_in[11];
  const float* W2   = (const float*)d_in[12];
  const float* b2   = (const float*)d_in[13];

  char* ws = (char*)d_ws;
  size_t off = 0;
  auto alloc = [&](size_t n) { size_t r = off; off += (n + 255) & ~(size_t)255; return r; };
  float* xn_f32  = (float*)(ws + alloc(4096ull * 1024 * 4));   // xn_h/xn_l, then x_attn
  u16*   xn_bf   = (u16*)(ws + alloc(4096ull * 1024 * 2));     // reused as h2
  u16*   wqkv_t  = (u16*)(ws + alloc(2048ull * 1024 * 2));     // [2048][1024] qk^T | v^T
  u16*   wo_t    = (u16*)(ws + alloc(1024ull * 1024 * 2));
  u16*   w1_t    = (u16*)(ws + alloc(4096ull * 1024 * 2));
  u16*   w2_t    = (u16*)(ws + alloc(4096ull * 1024 * 2));
  size_t qk_off  = alloc(4096ull * 2048 * 2);                  // qkv fused [4096][2048]
  u16*   qkvb    = (u16*)(ws + qk_off);
  float* w2r     = (float*)(ws + alloc(1024ull * 512 * 4));    // w2r_h/w2r_l f16
  float* rotated = (float*)(ws + alloc(4096ull * 512 * 4));    // reused as attn_comb
  int*   buckets = (int*)(ws + alloc(32ull * 4096 * 4));
  int*   stp     = (int*)(ws + alloc(32ull * 4096 * 4));
  int*   undo    = (int*)(ws + alloc(32ull * 4096 * 4));
  u16*   so      = (u16*)(ws + alloc(32ull * 4096 * 64 * 2));
  float* slog    = (float*)(ws + alloc(32ull * 4096 * 4));
  // aliases (lifetimes: donors dead before aliased writes)
  u16*   xn_h   = (u16*)xn_f32;          // LN1 out; dead after gemm_rot_split
  u16*   xn_l   = xn_h + 4096ull * 1024;
  float* x_attn = xn_f32;                // written after hash path done
  u16*   h2     = xn_bf;                 // written LN2; xn_bf dead after qkv gemm
  u16*   w2r_h  = (u16*)w2r;             // [512][1024] f16 hi
  u16*   w2r_l  = w2r_h + 512ull * 1024;
  u16*   attn_comb = (u16*)rotated;      // written combine; rotated dead after buckets
  u16*   f1 = (u16*)(ws + qk_off);       // 32MB spans qkvb..so; all dead before FFN1

  dim3 tb(32, 8);
  transpose_k<<<dim3(32, 32), tb, 0, stream>>>(Wqk, wqkv_t, 1024, 1024);
  transpose_k<<<dim3(32, 32), tb, 0, stream>>>(Wv, wqkv_t + 1024ull * 1024, 1024, 1024);
  transpose_k<<<dim3(32, 32), tb, 0, stream>>>(Wo, wo_t, 1024, 1024);
  transpose_k<<<dim3(128, 32), tb, 0, stream>>>(W1, w1_t, 1024, 4096);
  transpose_k<<<dim3(32, 128), tb, 0, stream>>>(W2, w2_t, 4096, 1024);

  ln_kernel<<<4096, 256, 0, stream>>>(x, ln1g, ln1b, xn_bf, xn_h, xn_l);

  // fused qk|v projection: [4096,1024] @ [2048,1024]^T -> [4096,2048]
  gemm_bf16<0><<<dim3(16, 32), 256, 0, stream>>>(xn_bf, wqkv_t, qkvb, nullptr, nullptr,
                                                 4096, 2048, 1024);

  w2r_kernel<<<2048, 256, 0, stream>>>(Wqk, rot, w2r_h, w2r_l);
  gemm_rot_split<<<dim3(8, 32), 256, 0, stream>>>(xn_h, xn_l, w2r_h, w2r_l, rotated);
  bucket_kernel<<<512, 256, 0, stream>>>(rotated, buckets);
  sort_kernel<<<32, 256, 0, stream>>>(buckets, stp, undo);
  attn_kernel<<<dim3(64, 32), 256, 0, stream>>>(qkvb, stp, so, slog);
  combine_kernel<<<dim3(512, 32), 256, 0, stream>>>(so, slog, undo, attn_comb);

  gemm_bf16_n64<1><<<dim3(16, 32), 256, 0, stream>>>(attn_comb, wo_t, x_attn, nullptr, x,
                                                     4096, 1024, 1024);
  ln_kernel<<<4096, 256, 0, stream>>>(x_attn, ln2g, ln2b, h2, nullptr, nullptr);
  // FFN1 on the 256^2 4-phase pipelined kernel: grid 16x16 = 256 blocks = 1/CU
  gemm_bf16_256<2><<<dim3(16, 16), 512, 0, stream>>>(h2, w1_t, f1, b1, nullptr,
                                                     4096, 4096, 1024);
  gemm_bf16_n64<3><<<dim3(16, 32), 256, 0, stream>>>(f1, w2_t, (float*)d_out, b2, x_attn,
                                                     4096, 1024, 4096);
}

// Round 12
// 280.298 us; speedup vs baseline: 1.1413x; 1.0621x over previous
//
#include <hip/hip_runtime.h>

typedef unsigned short u16;
typedef unsigned int u32;
typedef unsigned long long u64;
typedef __attribute__((ext_vector_type(8))) __bf16 bf16x8;
typedef __attribute__((ext_vector_type(8))) _Float16 f16x8;
typedef __attribute__((ext_vector_type(4))) float f32x4;

#define DEVI __device__ __forceinline__

DEVI float bf2f(u16 u) { u32 x = ((u32)u) << 16; return __uint_as_float(x); }
DEVI u16 f2bf(float f) {
  u32 u = __float_as_uint(f);
  return (u16)((u + 0x7FFFu + ((u >> 16) & 1u)) >> 16);
}
DEVI u16 h_bits(_Float16 h) { return __builtin_bit_cast(u16, h); }
DEVI void gload_lds16(const void* g, void* l) {
  __builtin_amdgcn_global_load_lds((const __attribute__((address_space(1))) void*)g,
                                   (__attribute__((address_space(3))) void*)l, 16, 0, 0);
}
// bijective XCD-aware block swizzle
DEVI void swz_block(int& bx, int& by) {
  int gx = gridDim.x;
  int nwg = gx * gridDim.y;
  int wg = blockIdx.y * gx + blockIdx.x;
  int q = nwg >> 3, rr = nwg & 7, xcd = wg & 7, idx = wg >> 3;
  int s = (xcd < rr ? xcd * (q + 1) : rr * (q + 1) + (xcd - rr) * q) + idx;
  bx = s % gx;
  by = s / gx;
}

// ---------------- transpose f32 -> bf16 (out[C][R] = bf16(in[R][C])) ----------------
__global__ __launch_bounds__(256) void transpose_k(const float* __restrict__ in,
                                                   u16* __restrict__ out, int R, int C) {
  __shared__ float tile[32][33];
  int c0 = blockIdx.x * 32, r0 = blockIdx.y * 32;
  int tx = threadIdx.x, ty = threadIdx.y;  // (32,8)
#pragma unroll
  for (int k = 0; k < 4; k++)
    tile[ty + 8 * k][tx] = in[(size_t)(r0 + ty + 8 * k) * C + c0 + tx];
  __syncthreads();
#pragma unroll
  for (int k = 0; k < 4; k++) {
    float v = tile[tx][ty + 8 * k];
    out[(size_t)(c0 + ty + 8 * k) * R + r0 + tx] = f2bf(v);
  }
}

// ---------------- LayerNorm: 1024 cols, one block per row ----------------
__global__ __launch_bounds__(256) void ln_kernel(const float* __restrict__ x,
                                                 const float* __restrict__ g,
                                                 const float* __restrict__ b,
                                                 u16* __restrict__ obf,
                                                 u16* __restrict__ oh,
                                                 u16* __restrict__ ol) {
  int row = blockIdx.x;
  const float* xr = x + (size_t)row * 1024;
  float vals[4];
  float s = 0.f, s2 = 0.f;
#pragma unroll
  for (int i = 0; i < 4; i++) {
    float v = xr[threadIdx.x + i * 256];
    vals[i] = v; s += v; s2 += v * v;
  }
#pragma unroll
  for (int off = 32; off > 0; off >>= 1) {
    s += __shfl_down(s, off);
    s2 += __shfl_down(s2, off);
  }
  __shared__ float red[8];
  int wid = threadIdx.x >> 6;
  if ((threadIdx.x & 63) == 0) { red[wid] = s; red[4 + wid] = s2; }
  __syncthreads();
  if (threadIdx.x == 0) {
    float a = red[0] + red[1] + red[2] + red[3];
    float a2 = red[4] + red[5] + red[6] + red[7];
    float mu = a * (1.0f / 1024.0f);
    red[0] = mu;
    red[1] = a2 * (1.0f / 1024.0f) - mu * mu;
  }
  __syncthreads();
  float mu = red[0];
  float inv = 1.0f / sqrtf(red[1] + 1e-5f);
#pragma unroll
  for (int i = 0; i < 4; i++) {
    int c = threadIdx.x + i * 256;
    float y = (vals[i] - mu) * inv * g[c] + b[c];
    if (obf) obf[(size_t)row * 1024 + c] = f2bf(y);
    if (oh) {
      _Float16 hh = (_Float16)y;
      _Float16 ll = (_Float16)(y - (float)hh);
      oh[(size_t)row * 1024 + c] = h_bits(hh);
      ol[(size_t)row * 1024 + c] = h_bits(ll);
    }
  }
}

// ---- W2r_t[n][c] = sum_d Wqk[c][h*64+d]*rot[d][rj], f64 acc, f16 hi/lo split -------
__global__ __launch_bounds__(256) void w2r_kernel(const float* __restrict__ wqk,
                                                  const float* __restrict__ rot,
                                                  u16* __restrict__ w2rh,
                                                  u16* __restrict__ w2rl) {
  int idx = blockIdx.x * 256 + threadIdx.x;  // < 512*1024
  int n = idx >> 10, c = idx & 1023;
  int h = n >> 5, rj = n & 31;
  const float* wp = wqk + (size_t)c * 1024 + h * 64;
  double acc = 0.0;
  for (int d = 0; d < 64; d++) acc += (double)wp[d] * (double)rot[d * 32 + rj];
  _Float16 hh = (_Float16)acc;
  _Float16 ll = (_Float16)(acc - (double)hh);
  w2rh[idx] = h_bits(hh);
  w2rl[idx] = h_bits(ll);
}

// ---- rotated[4096,512] = A @ B^T via f16-split MFMA: Ah*Bh + Ah*Bl + Al*Bh ---------
__global__ __launch_bounds__(256) void gemm_rot_split(const u16* __restrict__ Ah,
                                                      const u16* __restrict__ Al,
                                                      const u16* __restrict__ Bh,
                                                      const u16* __restrict__ Bl,
                                                      float* __restrict__ C) {
  __shared__ __align__(16) u16 Ash[128 * 32];
  __shared__ __align__(16) u16 Asl[128 * 32];
  __shared__ __align__(16) u16 Bsh[64 * 32];
  __shared__ __align__(16) u16 Bsl[64 * 32];
  int tid = threadIdx.x;
  int bx, by;
  swz_block(bx, by);
  int m0 = by * 128, n0 = bx * 64;
  int w = tid >> 6, l = tid & 63, lr = l & 15, g = l >> 4;
  int wm = w >> 1, wn = w & 1;
  f32x4 acc[4][2];
#pragma unroll
  for (int i = 0; i < 4; i++)
#pragma unroll
    for (int j = 0; j < 2; j++) { f32x4 z = {0.f, 0.f, 0.f, 0.f}; acc[i][j] = z; }
  for (int k0 = 0; k0 < 1024; k0 += 32) {
    __syncthreads();
#pragma unroll
    for (int e = 0; e < 2; e++) {
      int idx = e * 256 + tid;
      const u16* ga = Ah + (size_t)(m0 + (idx >> 2)) * 1024 + k0 + (idx & 3) * 8;
      gload_lds16(ga, &Ash[(e * 256 + w * 64) * 8]);
      const u16* gl = Al + (size_t)(m0 + (idx >> 2)) * 1024 + k0 + (idx & 3) * 8;
      gload_lds16(gl, &Asl[(e * 256 + w * 64) * 8]);
    }
    {
      const u16* gb = Bh + (size_t)(n0 + (tid >> 2)) * 1024 + k0 + (tid & 3) * 8;
      gload_lds16(gb, &Bsh[(w * 64) * 8]);
      const u16* gb2 = Bl + (size_t)(n0 + (tid >> 2)) * 1024 + k0 + (tid & 3) * 8;
      gload_lds16(gb2, &Bsl[(w * 64) * 8]);
    }
    __syncthreads();
    f16x8 ah[4], al[4], bh[2], bl[2];
#pragma unroll
    for (int mt = 0; mt < 4; mt++) {
      ah[mt] = *(const f16x8*)&Ash[(wm * 64 + mt * 16 + lr) * 32 + g * 8];
      al[mt] = *(const f16x8*)&Asl[(wm * 64 + mt * 16 + lr) * 32 + g * 8];
    }
#pragma unroll
    for (int nt = 0; nt < 2; nt++) {
      bh[nt] = *(const f16x8*)&Bsh[(wn * 32 + nt * 16 + lr) * 32 + g * 8];
      bl[nt] = *(const f16x8*)&Bsl[(wn * 32 + nt * 16 + lr) * 32 + g * 8];
    }
#pragma unroll
    for (int mt = 0; mt < 4; mt++)
#pragma unroll
      for (int nt = 0; nt < 2; nt++) {
        acc[mt][nt] = __builtin_amdgcn_mfma_f32_16x16x32_f16(ah[mt], bh[nt], acc[mt][nt], 0, 0, 0);
        acc[mt][nt] = __builtin_amdgcn_mfma_f32_16x16x32_f16(ah[mt], bl[nt], acc[mt][nt], 0, 0, 0);
        acc[mt][nt] = __builtin_amdgcn_mfma_f32_16x16x32_f16(al[mt], bh[nt], acc[mt][nt], 0, 0, 0);
      }
  }
#pragma unroll
  for (int mt = 0; mt < 4; mt++)
#pragma unroll
    for (int nt = 0; nt < 2; nt++)
#pragma unroll
      for (int r = 0; r < 4; r++) {
        int row = m0 + wm * 64 + mt * 16 + g * 4 + r;
        int col = n0 + wn * 32 + nt * 16 + lr;
        C[(size_t)row * 512 + col] = acc[mt][nt][r];
      }
}

// ---------------- buckets: argmax over [v, -v] of 16 projections ----------------
__global__ __launch_bounds__(256) void bucket_kernel(const float* __restrict__ rotated,
                                                     int* __restrict__ buckets) {
  int gid = blockIdx.x * 256 + threadIdx.x;  // < 131072
  int bh = gid >> 12;
  int rem = gid & 4095;
  int r = rem >> 11, t = rem & 2047;
  int b = bh >> 4, h = bh & 15;
  const float* rp = rotated + (size_t)(b * 2048 + t) * 512 + h * 32 + r * 16;
  float v16[16];
#pragma unroll
  for (int j = 0; j < 16; j++) v16[j] = rp[j];
  float bv = v16[0];
  int bi = 0;
#pragma unroll
  for (int jj = 1; jj < 32; jj++) {
    float v = (jj < 16) ? v16[jj] : -v16[jj - 16];
    if (v > bv) { bv = v; bi = jj; }
  }
  buckets[bh * 4096 + r * 2048 + t] = bi + r * 32;
}

// ------- stable counting sort per (b,h): wave-parallel multisplit (ballot) ---------
__global__ __launch_bounds__(256) void sort_kernel(const int* __restrict__ buckets,
                                                   int* __restrict__ st,
                                                   int* __restrict__ undo) {
  int bh = blockIdx.x;
  __shared__ unsigned char bk[4096];
  __shared__ unsigned char rnk[4096];
  __shared__ int cnt[64 * 64];  // [chunk][bucket]
  __shared__ int base[64];
  int tid = threadIdx.x;
  int w = tid >> 6, lane = tid & 63;
  for (int i = tid; i < 4096; i += 256) bk[i] = (unsigned char)buckets[bh * 4096 + i];
  for (int i = tid; i < 4096; i += 256) cnt[i] = 0;
  __syncthreads();
  u64 lmask = (lane == 63) ? 0x7FFFFFFFFFFFFFFFull : ((1ull << lane) - 1ull);
#pragma unroll
  for (int it = 0; it < 16; ++it) {
    int c = w * 16 + it;
    int i = c * 64 + lane;
    int b = bk[i];
    u64 m = ~0ull;
#pragma unroll
    for (int k = 0; k < 6; k++) {
      u64 bal = __ballot((b >> k) & 1);
      m &= ((b >> k) & 1) ? bal : ~bal;
    }
    int r = __popcll(m & lmask);
    rnk[i] = (unsigned char)r;
    if (r == 0) cnt[c * 64 + b] = __popcll(m);
  }
  __syncthreads();
  if (tid < 64) {
    int acc = 0;
    for (int c = 0; c < 64; c++) {
      int t = cnt[c * 64 + tid];
      cnt[c * 64 + tid] = acc;
      acc += t;
    }
    base[tid] = acc;
  }
  __syncthreads();
  if (tid == 0) {
    int acc = 0;
    for (int b = 0; b < 64; b++) { int t = base[b]; base[b] = acc; acc += t; }
  }
  __syncthreads();
#pragma unroll
  for (int it = 0; it < 16; ++it) {
    int c = w * 16 + it;
    int i = c * 64 + lane;
    int b = bk[i];
    int pos = base[b] + cnt[c * 64 + b] + rnk[i];
    st[bh * 4096 + pos] = i & 2047;
    undo[bh * 4096 + i] = pos;
  }
}

// ------- chunked LSH attention: qkv fused layout [B*T][2048] (qk | v) -------
__global__ __launch_bounds__(256) void attn_kernel(const u16* __restrict__ qkv,
                                                   const int* __restrict__ st,
                                                   u16* __restrict__ so,
                                                   float* __restrict__ slog) {
  const int c = blockIdx.x;   // 0..63
  const int bh = blockIdx.y;  // 0..31
  const int b = bh >> 4, h = bh & 15;
  __shared__ __align__(16) u16 Q[64 * 72];
  __shared__ __align__(16) u16 Kl[128 * 72];
  __shared__ __align__(16) u16 Vt[64 * 136];
  __shared__ __align__(16) u16 P[64 * 136];
  __shared__ int bts[128];
  int tid = threadIdx.x;
  {
    int j = tid >> 1, half = tid & 1;
    int cc = (j < 64) ? c : ((c + 63) & 63);
    int t = st[bh * 4096 + cc * 64 + (j & 63)];
    size_t base = ((size_t)(b * 2048 + t)) * 2048 + h * 64 + half * 32;
    __align__(16) u16 raw[32];
    *(uint4*)(&raw[0]) = *(const uint4*)(qkv + base);
    *(uint4*)(&raw[8]) = *(const uint4*)(qkv + base + 8);
    *(uint4*)(&raw[16]) = *(const uint4*)(qkv + base + 16);
    *(uint4*)(&raw[24]) = *(const uint4*)(qkv + base + 24);
    float fv[32];
    float ss = 0.f;
#pragma unroll
    for (int e = 0; e < 32; e++) { fv[e] = bf2f(raw[e]); ss += fv[e] * fv[e]; }
    ss += __shfl_xor(ss, 1);
    float scale = 1.0f / (sqrtf(ss) + 1e-9f);
#pragma unroll
    for (int e = 0; e < 32; e++) Kl[j * 72 + half * 32 + e] = f2bf(fv[e] * scale);
    if (j < 64) {
#pragma unroll
      for (int e = 0; e < 32; e++) Q[j * 72 + half * 32 + e] = raw[e];
    }
    if (half == 0) bts[j] = t;
    __align__(16) u16 vr[32];
    *(uint4*)(&vr[0]) = *(const uint4*)(qkv + base + 1024);
    *(uint4*)(&vr[8]) = *(const uint4*)(qkv + base + 1032);
    *(uint4*)(&vr[16]) = *(const uint4*)(qkv + base + 1040);
    *(uint4*)(&vr[24]) = *(const uint4*)(qkv + base + 1048);
#pragma unroll
    for (int e = 0; e < 32; e++) Vt[(half * 32 + e) * 136 + j] = vr[e];
  }
  __syncthreads();
  int w = tid >> 6, l = tid & 63;
  int lr = l & 15, g = l >> 4;
  bf16x8 aq0 = *(const bf16x8*)&Q[(w * 16 + lr) * 72 + g * 8];
  bf16x8 aq1 = *(const bf16x8*)&Q[(w * 16 + lr) * 72 + 32 + g * 8];
  float dd[8][4];
#pragma unroll
  for (int n = 0; n < 8; n++) {
    f32x4 acc = {0.f, 0.f, 0.f, 0.f};
    bf16x8 b0 = *(const bf16x8*)&Kl[(n * 16 + lr) * 72 + g * 8];
    acc = __builtin_amdgcn_mfma_f32_16x16x32_bf16(aq0, b0, acc, 0, 0, 0);
    bf16x8 b1 = *(const bf16x8*)&Kl[(n * 16 + lr) * 72 + 32 + g * 8];
    acc = __builtin_amdgcn_mfma_f32_16x16x32_bf16(aq1, b1, acc, 0, 0, 0);
#pragma unroll
    for (int r = 0; r < 4; r++) dd[n][r] = acc[r];
  }
  int btq[4];
#pragma unroll
  for (int r = 0; r < 4; r++) btq[r] = bts[w * 16 + g * 4 + r];
  float mrow[4] = {-3e38f, -3e38f, -3e38f, -3e38f};
#pragma unroll
  for (int n = 0; n < 8; n++) {
    int btk = bts[n * 16 + lr];
#pragma unroll
    for (int r = 0; r < 4; r++) {
      float v = dd[n][r] * 0.125f;
      if (btq[r] == btk) v = -1e5f;
      dd[n][r] = v;
      mrow[r] = fmaxf(mrow[r], v);
    }
  }
#pragma unroll
  for (int off = 1; off < 16; off <<= 1)
#pragma unroll
    for (int r = 0; r < 4; r++) mrow[r] = fmaxf(mrow[r], __shfl_xor(mrow[r], off));
  float se[4] = {0.f, 0.f, 0.f, 0.f};
#pragma unroll
  for (int n = 0; n < 8; n++)
#pragma unroll
    for (int r = 0; r < 4; r++) se[r] += expf(dd[n][r] - mrow[r]);
#pragma unroll
  for (int off = 1; off < 16; off <<= 1)
#pragma unroll
    for (int r = 0; r < 4; r++) se[r] += __shfl_xor(se[r], off);
  float lse[4];
#pragma unroll
  for (int r = 0; r < 4; r++) lse[r] = mrow[r] + logf(se[r]);
#pragma unroll
  for (int n = 0; n < 8; n++)
#pragma unroll
    for (int r = 0; r < 4; r++) {
      float p = expf(dd[n][r] - lse[r]);
      P[(w * 16 + g * 4 + r) * 136 + n * 16 + lr] = f2bf(p);
    }
  if (lr == 0) {
#pragma unroll
    for (int r = 0; r < 4; r++)
      slog[bh * 4096 + c * 64 + w * 16 + g * 4 + r] = lse[r];
  }
  __syncthreads();
  f32x4 o[4];
#pragma unroll
  for (int n2 = 0; n2 < 4; n2++) { f32x4 z = {0.f, 0.f, 0.f, 0.f}; o[n2] = z; }
#pragma unroll
  for (int ks = 0; ks < 4; ks++) {
    bf16x8 ap = *(const bf16x8*)&P[(w * 16 + lr) * 136 + ks * 32 + g * 8];
#pragma unroll
    for (int n2 = 0; n2 < 4; n2++) {
      bf16x8 bv = *(const bf16x8*)&Vt[(n2 * 16 + lr) * 136 + ks * 32 + g * 8];
      o[n2] = __builtin_amdgcn_mfma_f32_16x16x32_bf16(ap, bv, o[n2], 0, 0, 0);
    }
  }
#pragma unroll
  for (int n2 = 0; n2 < 4; n2++)
#pragma unroll
    for (int r = 0; r < 4; r++)
      so[((size_t)bh * 4096 + c * 64 + w * 16 + g * 4 + r) * 64 + n2 * 16 + lr] =
          f2bf(o[n2][r]);
}

// ---------------- combine hash rounds + unsort ----------------
__global__ __launch_bounds__(256) void combine_kernel(const u16* __restrict__ so,
                                                      const float* __restrict__ slog,
                                                      const int* __restrict__ undo,
                                                      u16* __restrict__ attn_comb) {
  int bh = blockIdx.y;
  int b = bh >> 4, h = bh & 15;
  int t = blockIdx.x * 4 + (threadIdx.x >> 6);
  int d = threadIdx.x & 63;
  int j0 = undo[bh * 4096 + t];
  int j1 = undo[bh * 4096 + 2048 + t];
  float l0 = slog[bh * 4096 + j0], l1 = slog[bh * 4096 + j1];
  float m = fmaxf(l0, l1);
  float e0 = expf(l0 - m), e1 = expf(l1 - m);
  float inv = 1.0f / (e0 + e1);
  float o = (e0 * inv) * bf2f(so[((size_t)bh * 4096 + j0) * 64 + d]) +
            (e1 * inv) * bf2f(so[((size_t)bh * 4096 + j1) * 64 + d]);
  attn_comb[((size_t)(b * 2048 + t)) * 1024 + h * 64 + d] = f2bf(o);
}

// ---- bf16 MFMA GEMM, 128x128 tile, BK=32, 2-buf, ONE barrier per K-tile -----------
// Guide's minimum-2-phase recipe: STAGE(nxt,t+1) at window top; reads+MFMAs on cur;
// vmcnt(0); single s_barrier. Safety: wave reaches barrier only after its MFMAs
// (which force ds_read completion); barrier crossing makes staged nxt visible.
template <int EPI>
__global__ __launch_bounds__(256) void gemm_bf16(const u16* __restrict__ A,
                                                 const u16* __restrict__ Bt,
                                                 void* __restrict__ Cv,
                                                 const float* __restrict__ bias,
                                                 const float* __restrict__ resid,
                                                 int M, int N, int K) {
  __shared__ __align__(16) u16 As[2][128 * 32];
  __shared__ __align__(16) u16 Bs[2][128 * 32];
  int tid = threadIdx.x;
  int bx, by;
  swz_block(bx, by);
  int m0 = by * 128, n0 = bx * 128;
  int w = tid >> 6, l = tid & 63, lr = l & 15, g = l >> 4;
  int wm = w >> 1, wn = w & 1;
  int sw = lr & 3;
  f32x4 acc[4][4];
#pragma unroll
  for (int i = 0; i < 4; i++)
#pragma unroll
    for (int j = 0; j < 4; j++) { f32x4 z = {0.f, 0.f, 0.f, 0.f}; acc[i][j] = z; }

  auto stage = [&](int buf, int k0) {
#pragma unroll
    for (int e = 0; e < 2; e++) {
      int idx = e * 256 + tid;
      int row = idx >> 2;
      int slot = (idx & 3) ^ (row & 3);
      gload_lds16(A + (size_t)(m0 + row) * K + k0 + slot * 8,
                  &As[buf][(e * 256 + w * 64) * 8]);
      gload_lds16(Bt + (size_t)(n0 + row) * K + k0 + slot * 8,
                  &Bs[buf][(e * 256 + w * 64) * 8]);
    }
  };

  const int NT = K >> 5;
  stage(0, 0);
  asm volatile("s_waitcnt vmcnt(0)" ::: "memory");
  __builtin_amdgcn_s_barrier();
  for (int t = 0; t < NT; ++t) {
    int cur = t & 1;
    if (t + 1 < NT) stage(cur ^ 1, (t + 1) << 5);
    bf16x8 af[4], bfr[4];
#pragma unroll
    for (int mt = 0; mt < 4; mt++)
      af[mt] = *(const bf16x8*)&As[cur][(wm * 64 + mt * 16 + lr) * 32 + (g ^ sw) * 8];
#pragma unroll
    for (int nt = 0; nt < 4; nt++)
      bfr[nt] = *(const bf16x8*)&Bs[cur][(wn * 64 + nt * 16 + lr) * 32 + (g ^ sw) * 8];
#pragma unroll
    for (int mt = 0; mt < 4; mt++)
#pragma unroll
      for (int nt = 0; nt < 4; nt++)
        acc[mt][nt] =
            __builtin_amdgcn_mfma_f32_16x16x32_bf16(af[mt], bfr[nt], acc[mt][nt], 0, 0, 0);
    asm volatile("s_waitcnt vmcnt(0)" ::: "memory");
    __builtin_amdgcn_s_barrier();
  }
#pragma unroll
  for (int mt = 0; mt < 4; mt++)
#pragma unroll
    for (int nt = 0; nt < 4; nt++)
#pragma unroll
      for (int r = 0; r < 4; r++) {
        int row = m0 + wm * 64 + mt * 16 + g * 4 + r;
        int col = n0 + wn * 64 + nt * 16 + lr;
        float v = acc[mt][nt][r];
        if constexpr (EPI == 1) {
          v += resid[(size_t)row * N + col];
          ((float*)Cv)[(size_t)row * N + col] = v;
        } else if constexpr (EPI == 2) {
          v += bias[col];
          v = fmaxf(v, 0.f);
          ((u16*)Cv)[(size_t)row * N + col] = f2bf(v);
        } else if constexpr (EPI == 3) {
          v += bias[col] + resid[(size_t)row * N + col];
          ((float*)Cv)[(size_t)row * N + col] = v;
        } else {
          ((u16*)Cv)[(size_t)row * N + col] = f2bf(v);
        }
      }
}

// ---- bf16 MFMA GEMM, 128x64 tile, BK=64, 2-buf, ONE barrier per K-tile ------------
template <int EPI>
__global__ __launch_bounds__(256) void gemm_bf16_n64(const u16* __restrict__ A,
                                                     const u16* __restrict__ Bt,
                                                     void* __restrict__ Cv,
                                                     const float* __restrict__ bias,
                                                     const float* __restrict__ resid,
                                                     int M, int N, int K) {
  __shared__ __align__(16) u16 As[2][128 * 64];
  __shared__ __align__(16) u16 Bs[2][64 * 64];
  int tid = threadIdx.x;
  int bx, by;
  swz_block(bx, by);
  int m0 = by * 128, n0 = bx * 64;
  int w = tid >> 6, l = tid & 63, lr = l & 15, g = l >> 4;
  int swa = lr & 7;
  f32x4 acc[2][4];
#pragma unroll
  for (int i = 0; i < 2; i++)
#pragma unroll
    for (int j = 0; j < 4; j++) { f32x4 z = {0.f, 0.f, 0.f, 0.f}; acc[i][j] = z; }

  auto stage = [&](int buf, int k0) {
#pragma unroll
    for (int e = 0; e < 4; e++) {
      int idx = e * 256 + tid;
      int row = idx >> 3, s = idx & 7;
      gload_lds16(A + (size_t)(m0 + row) * K + k0 + ((s ^ (row & 7)) * 8),
                  &As[buf][(e * 256 + w * 64) * 8]);
    }
#pragma unroll
    for (int e = 0; e < 2; e++) {
      int idx = e * 256 + tid;
      int row = idx >> 3, s = idx & 7;
      gload_lds16(Bt + (size_t)(n0 + row) * K + k0 + ((s ^ (row & 7)) * 8),
                  &Bs[buf][(e * 256 + w * 64) * 8]);
    }
  };

  const int NT = K >> 6;
  stage(0, 0);
  asm volatile("s_waitcnt vmcnt(0)" ::: "memory");
  __builtin_amdgcn_s_barrier();
  for (int t = 0; t < NT; ++t) {
    int cur = t & 1;
    if (t + 1 < NT) stage(cur ^ 1, (t + 1) << 6);
    bf16x8 af[2][2], bfr[4][2];
#pragma unroll
    for (int mt = 0; mt < 2; mt++)
#pragma unroll
      for (int ks = 0; ks < 2; ks++)
        af[mt][ks] = *(const bf16x8*)&As[cur][(w * 32 + mt * 16 + lr) * 64 +
                                             (((ks * 4 + g) ^ swa) * 8)];
#pragma unroll
    for (int nt = 0; nt < 4; nt++)
#pragma unroll
      for (int ks = 0; ks < 2; ks++)
        bfr[nt][ks] = *(const bf16x8*)&Bs[cur][(nt * 16 + lr) * 64 +
                                              (((ks * 4 + g) ^ swa) * 8)];
#pragma unroll
    for (int ks = 0; ks < 2; ks++)
#pragma unroll
      for (int mt = 0; mt < 2; mt++)
#pragma unroll
        for (int nt = 0; nt < 4; nt++)
          acc[mt][nt] = __builtin_amdgcn_mfma_f32_16x16x32_bf16(af[mt][ks], bfr[nt][ks],
                                                                acc[mt][nt], 0, 0, 0);
    asm volatile("s_waitcnt vmcnt(0)" ::: "memory");
    __builtin_amdgcn_s_barrier();
  }
#pragma unroll
  for (int mt = 0; mt < 2; mt++)
#pragma unroll
    for (int nt = 0; nt < 4; nt++)
#pragma unroll
      for (int r = 0; r < 4; r++) {
        int row = m0 + w * 32 + mt * 16 + g * 4 + r;
        int col = n0 + nt * 16 + lr;
        float v = acc[mt][nt][r];
        if constexpr (EPI == 1) {
          v += resid[(size_t)row * N + col];
          ((float*)Cv)[(size_t)row * N + col] = v;
        } else if constexpr (EPI == 2) {
          v += bias[col];
          v = fmaxf(v, 0.f);
          ((u16*)Cv)[(size_t)row * N + col] = f2bf(v);
        } else if constexpr (EPI == 3) {
          v += bias[col] + resid[(size_t)row * N + col];
          ((float*)Cv)[(size_t)row * N + col] = v;
        } else {
          ((u16*)Cv)[(size_t)row * N + col] = f2bf(v);
        }
      }
}

// ---- bf16 MFMA GEMM, 256x256, BK=64, 8 waves, 2-buf, ONE barrier per K-tile -------
// Full tile staged at window top (8 gloads/thread); 32 ds_reads + 64 MFMAs in one
// window (snake quadrant order reuses operand regs); vmcnt(0) + single barrier.
// NOTE: dual-fragment read-ahead (r9/r10) spills (VGPR cap 128) — keep single set.
#define BARR __builtin_amdgcn_s_barrier()
#define LOAD_A_Q(curv, qmv)                                                         \
  {                                                                                 \
    _Pragma("unroll") for (int mf = 0; mf < 4; mf++) {                              \
      _Pragma("unroll") for (int ks = 0; ks < 2; ks++) {                            \
        int row_ = wm * 128 + (qmv)*64 + mf * 16 + lr;                              \
        a[mf][ks] = *(const bf16x8*)&Al[curv][row_ * 64 +                           \
                                              (((ks * 4 + g) ^ (lr & 7)) * 8)];     \
      }                                                                             \
    }                                                                               \
  }
#define LOAD_B_Q(curv, qnv)                                                         \
  {                                                                                 \
    _Pragma("unroll") for (int nf = 0; nf < 2; nf++) {                              \
      _Pragma("unroll") for (int ks = 0; ks < 2; ks++) {                            \
        int row_ = wn * 64 + (qnv)*32 + nf * 16 + lr;                               \
        bfr[nf][ks] = *(const bf16x8*)&Bl[curv][row_ * 64 +                         \
                                                (((ks * 4 + g) ^ (lr & 7)) * 8)];   \
      }                                                                             \
    }                                                                               \
  }
#define MFMA_Q(QM, QN)                                                              \
  {                                                                                 \
    _Pragma("unroll") for (int ks = 0; ks < 2; ks++) {                              \
      _Pragma("unroll") for (int mf = 0; mf < 4; mf++) {                            \
        _Pragma("unroll") for (int nf = 0; nf < 2; nf++) {                          \
          acc[(QM)*4 + mf][(QN)*2 + nf] = __builtin_amdgcn_mfma_f32_16x16x32_bf16(  \
              a[mf][ks], bfr[nf][ks], acc[(QM)*4 + mf][(QN)*2 + nf], 0, 0, 0);      \
        }                                                                           \
      }                                                                             \
    }                                                                               \
  }

template <int EPI>
__global__ __launch_bounds__(512, 2) void gemm_bf16_256(const u16* __restrict__ A,
                                                        const u16* __restrict__ Bt,
                                                        void* __restrict__ Cv,
                                                        const float* __restrict__ bias,
                                                        const float* __restrict__ resid,
                                                        int M, int N, int K) {
  __shared__ __align__(16) u16 Al[2][256 * 64];
  __shared__ __align__(16) u16 Bl[2][256 * 64];
  int tid = threadIdx.x;
  int bx, by;
  swz_block(bx, by);
  int m0 = by * 256, n0 = bx * 256;
  int w = tid >> 6, l = tid & 63, lr = l & 15, g = l >> 4;
  int wm = w >> 2, wn = w & 3;
  f32x4 acc[8][4];
#pragma unroll
  for (int i = 0; i < 8; i++)
#pragma unroll
    for (int j = 0; j < 4; j++) { f32x4 z = {0.f, 0.f, 0.f, 0.f}; acc[i][j] = z; }

  // staging unit u: 0=A qm0 (rows 0-63,128-191), 2=A qm1 (64-127,192-255)
  //                 1=B qn0 (32-row stripes at 0,64,128,192), 3=B qn1 (+32)
  auto stage_unit = [&](int u, int buf, int k0) {
#pragma unroll
    for (int j = 0; j < 2; j++) {
      int r = j * 64 + (tid >> 3);
      int s = tid & 7;
      int co = (s ^ (r & 7)) * 8;
      int r0 = j * 64 + (w << 3);
      const u16* src;
      u16* dst;
      if (u == 0) {
        int row = (r < 64) ? r : r + 64;
        int row0 = (r0 < 64) ? r0 : r0 + 64;
        src = A + (size_t)(m0 + row) * K + k0 + co;
        dst = &Al[buf][row0 * 64];
      } else if (u == 2) {
        int row = (r < 64) ? r + 64 : r + 128;
        int row0 = (r0 < 64) ? r0 + 64 : r0 + 128;
        src = A + (size_t)(m0 + row) * K + k0 + co;
        dst = &Al[buf][row0 * 64];
      } else if (u == 1) {
        int row = ((r >> 5) << 6) + (r & 31);
        int row0 = ((r0 >> 5) << 6) + (r0 & 31);
        src = Bt + (size_t)(n0 + row) * K + k0 + co;
        dst = &Bl[buf][row0 * 64];
      } else {
        int row = ((r >> 5) << 6) + 32 + (r & 31);
        int row0 = ((r0 >> 5) << 6) + 32 + (r0 & 31);
        src = Bt + (size_t)(n0 + row) * K + k0 + co;
        dst = &Bl[buf][row0 * 64];
      }
      gload_lds16(src, dst);
    }
  };

  bf16x8 a[4][2], bfr[2][2];
  const int NT = K >> 6;
  stage_unit(0, 0, 0);
  stage_unit(1, 0, 0);
  stage_unit(2, 0, 0);
  stage_unit(3, 0, 0);
  asm volatile("s_waitcnt vmcnt(0)" ::: "memory");
  BARR;
  for (int t = 0; t < NT; ++t) {
    int cur = t & 1, nxt = cur ^ 1;
    int k1 = (t + 1) << 6;
    if (t + 1 < NT) {
      stage_unit(0, nxt, k1);
      stage_unit(1, nxt, k1);
      stage_unit(2, nxt, k1);
      stage_unit(3, nxt, k1);
    }
    // snake quadrant order: (0,0) -> (1,0) -> (1,1) -> (0,1); operand reuse
    LOAD_A_Q(cur, 0);
    LOAD_B_Q(cur, 0);
    MFMA_Q(0, 0);
    LOAD_A_Q(cur, 1);
    MFMA_Q(1, 0);
    LOAD_B_Q(cur, 1);
    MFMA_Q(1, 1);
    LOAD_A_Q(cur, 0);
    MFMA_Q(0, 1);
    asm volatile("s_waitcnt vmcnt(0)" ::: "memory");
    BARR;
  }
#pragma unroll
  for (int mf = 0; mf < 8; mf++)
#pragma unroll
    for (int nf = 0; nf < 4; nf++)
#pragma unroll
      for (int r = 0; r < 4; r++) {
        int row = m0 + wm * 128 + mf * 16 + g * 4 + r;
        int col = n0 + wn * 64 + nf * 16 + lr;
        float v = acc[mf][nf][r];
        if constexpr (EPI == 1) {
          v += resid[(size_t)row * N + col];
          ((float*)Cv)[(size_t)row * N + col] = v;
        } else if constexpr (EPI == 2) {
          v += bias[col];
          v = fmaxf(v, 0.f);
          ((u16*)Cv)[(size_t)row * N + col] = f2bf(v);
        } else if constexpr (EPI == 3) {
          v += bias[col] + resid[(size_t)row * N + col];
          ((float*)Cv)[(size_t)row * N + col] = v;
        } else {
          ((u16*)Cv)[(size_t)row * N + col] = f2bf(v);
        }
      }
}

// ==================================================================================
extern "C" void kernel_launch(void* const* d_in, const int* in_sizes, int n_in,
                              void* d_out, int out_size, void* d_ws, size_t ws_size,
                              hipStream_t stream) {
  (void)in_sizes; (void)n_in; (void)out_size; (void)ws_size;
  const float* x    = (const float*)d_in[0];
  const float* ln1g = (const float*)d_in[2];
  const float* ln1b = (const float*)d_in[3];
  const float* ln2g = (const float*)d_in[4];
  const float* ln2b = (const float*)d_in[5];
  const float* Wqk  = (const float*)d_in[6];
  const float* Wv   = (const float*)d_in[7];
  const float* Wo   = (const float*)d_in[8];
  const float* rot  = (const float*)d_in[9];
  const float* W1   = (const float*)d_in[10];
  const float* b1   = (const float*)d_in[11];
  const float* W2   = (const float*)d_in[12];
  const float* b2   = (const float*)d_in[13];

  char* ws = (char*)d_ws;
  size_t off = 0;
  auto alloc = [&](size_t n) { size_t r = off; off += (n + 255) & ~(size_t)255; return r; };
  float* xn_f32  = (float*)(ws + alloc(4096ull * 1024 * 4));   // xn_h/xn_l, then x_attn
  u16*   xn_bf   = (u16*)(ws + alloc(4096ull * 1024 * 2));     // reused as h2
  u16*   wqkv_t  = (u16*)(ws + alloc(2048ull * 1024 * 2));     // [2048][1024] qk^T | v^T
  u16*   wo_t    = (u16*)(ws + alloc(1024ull * 1024 * 2));
  u16*   w1_t    = (u16*)(ws + alloc(4096ull * 1024 * 2));
  u16*   w2_t    = (u16*)(ws + alloc(4096ull * 1024 * 2));
  size_t qk_off  = alloc(4096ull * 2048 * 2);                  // qkv fused [4096][2048]
  u16*   qkvb    = (u16*)(ws + qk_off);
  float* w2r     = (float*)(ws + alloc(1024ull * 512 * 4));    // w2r_h/w2r_l f16
  float* rotated = (float*)(ws + alloc(4096ull * 512 * 4));    // reused as attn_comb
  int*   buckets = (int*)(ws + alloc(32ull * 4096 * 4));
  int*   stp     = (int*)(ws + alloc(32ull * 4096 * 4));
  int*   undo    = (int*)(ws + alloc(32ull * 4096 * 4));
  u16*   so      = (u16*)(ws + alloc(32ull * 4096 * 64 * 2));
  float* slog    = (float*)(ws + alloc(32ull * 4096 * 4));
  // aliases (lifetimes: donors dead before aliased writes)
  u16*   xn_h   = (u16*)xn_f32;          // LN1 out; dead after gemm_rot_split
  u16*   xn_l   = xn_h + 4096ull * 1024;
  float* x_attn = xn_f32;                // written after hash path done
  u16*   h2     = xn_bf;                 // written LN2; xn_bf dead after qkv gemm
  u16*   w2r_h  = (u16*)w2r;             // [512][1024] f16 hi
  u16*   w2r_l  = w2r_h + 512ull * 1024;
  u16*   attn_comb = (u16*)rotated;      // written combine; rotated dead after buckets
  u16*   f1 = (u16*)(ws + qk_off);       // 32MB spans qkvb..so; all dead before FFN1

  dim3 tb(32, 8);
  transpose_k<<<dim3(32, 32), tb, 0, stream>>>(Wqk, wqkv_t, 1024, 1024);
  transpose_k<<<dim3(32, 32), tb, 0, stream>>>(Wv, wqkv_t + 1024ull * 1024, 1024, 1024);
  transpose_k<<<dim3(32, 32), tb, 0, stream>>>(Wo, wo_t, 1024, 1024);
  transpose_k<<<dim3(128, 32), tb, 0, stream>>>(W1, w1_t, 1024, 4096);
  transpose_k<<<dim3(32, 128), tb, 0, stream>>>(W2, w2_t, 4096, 1024);

  ln_kernel<<<4096, 256, 0, stream>>>(x, ln1g, ln1b, xn_bf, xn_h, xn_l);

  // fused qk|v projection: [4096,1024] @ [2048,1024]^T -> [4096,2048]
  gemm_bf16<0><<<dim3(16, 32), 256, 0, stream>>>(xn_bf, wqkv_t, qkvb, nullptr, nullptr,
                                                 4096, 2048, 1024);

  w2r_kernel<<<2048, 256, 0, stream>>>(Wqk, rot, w2r_h, w2r_l);
  gemm_rot_split<<<dim3(8, 32), 256, 0, stream>>>(xn_h, xn_l, w2r_h, w2r_l, rotated);
  bucket_kernel<<<512, 256, 0, stream>>>(rotated, buckets);
  sort_kernel<<<32, 256, 0, stream>>>(buckets, stp, undo);
  attn_kernel<<<dim3(64, 32), 256, 0, stream>>>(qkvb, stp, so, slog);
  combine_kernel<<<dim3(512, 32), 256, 0, stream>>>(so, slog, undo, attn_comb);

  gemm_bf16_n64<1><<<dim3(16, 32), 256, 0, stream>>>(attn_comb, wo_t, x_attn, nullptr, x,
                                                     4096, 1024, 1024);
  ln_kernel<<<4096, 256, 0, stream>>>(x_attn, ln2g, ln2b, h2, nullptr, nullptr);
  // FFN1 on the 256^2 single-barrier pipelined kernel: grid 16x16 = 256 blocks = 1/CU
  gemm_bf16_256<2><<<dim3(16, 16), 512, 0, stream>>>(h2, w1_t, f1, b1, nullptr,
                                                     4096, 4096, 1024);
  gemm_bf16_n64<3><<<dim3(16, 32), 256, 0, stream>>>(f1, w2_t, (float*)d_out, b2, x_attn,
                                                     4096, 1024, 4096);
}